// Round 3
// baseline (811.597 us; speedup 1.0000x reference)
//
#include <hip/hip_runtime.h>
#include <stdint.h>

#define B_  4
#define S_  2048
#define D_  2048
#define H_  16
#define DH_ 128
#define M_  (B_*S_)

typedef unsigned short u16;
typedef __bf16 bf16x8 __attribute__((ext_vector_type(8)));
typedef float  f32x4  __attribute__((ext_vector_type(4)));
typedef u16    u16x4  __attribute__((ext_vector_type(4)));

__device__ __forceinline__ u16 f2bf(float f){
  unsigned x = __float_as_uint(f);
  x += 0x7fffu + ((x >> 16) & 1u);          // RNE
  return (u16)(x >> 16);
}

// v_cvt_pk_bf16_f32: D[15:0]=bf16(lo), D[31:16]=bf16(hi). No HIP builtin (m240).
__device__ __forceinline__ unsigned pkbf(float lo, float hi){
  unsigned r;
  asm("v_cvt_pk_bf16_f32 %0, %1, %2" : "=v"(r) : "v"(lo), "v"(hi));
  return r;
}

// Async global->LDS, 16B per lane. LDS dest = wave-uniform base + lane*16.
__device__ __forceinline__ void stage16(const void* g, void* lds_base){
  __builtin_amdgcn_global_load_lds(
      (const __attribute__((address_space(1))) void*)g,
      (__attribute__((address_space(3))) void*)lds_base, 16, 0, 0);
}

__device__ __forceinline__ f32x4 mfma16(bf16x8 a, bf16x8 b, f32x4 c){
  return __builtin_amdgcn_mfma_f32_16x16x32_bf16(a, b, c, 0, 0, 0);
}

// ---------------- fp32 -> bf16 cast (vectorized) ----------------
__global__ void cvt_bf16(const float* __restrict__ s, u16* __restrict__ d, int n4){
  int i = blockIdx.x * 256 + threadIdx.x;
  if (i >= n4) return;
  float4 f = ((const float4*)s)[i];
  u16x4 u = { f2bf(f.x), f2bf(f.y), f2bf(f.z), f2bf(f.w) };
  ((u16x4*)d)[i] = u;
}

// ---------------- W [K][N] fp32 -> WT [N][K] bf16 ----------------
__global__ void transpose_bf(const float* __restrict__ W, u16* __restrict__ WT, int K, int N){
  __shared__ float tl[32][33];
  int n0 = blockIdx.x * 32, k0 = blockIdx.y * 32;
  int tx = threadIdx.x, ty = threadIdx.y;     // block (32,8)
  for (int r = 0; r < 4; r++)
    tl[ty + 8*r][tx] = W[(size_t)(k0 + ty + 8*r) * N + n0 + tx];
  __syncthreads();
  for (int r = 0; r < 4; r++)
    WT[(size_t)(n0 + ty + 8*r) * K + k0 + tx] = f2bf(tl[tx][ty + 8*r]);
}

// -------- vh [B*S][DH] bf16 -> vhT [B][DH][S] bf16 --------
__global__ void transpose_vh(const u16* __restrict__ vh, u16* __restrict__ vhT){
  __shared__ u16 tl[32][33];
  int b = blockIdx.z, d0 = blockIdx.x * 32, s0 = blockIdx.y * 32;
  int tx = threadIdx.x, ty = threadIdx.y;     // block (32,8)
  for (int r = 0; r < 4; r++)
    tl[ty + 8*r][tx] = vh[(size_t)(b * S_ + s0 + ty + 8*r) * DH_ + d0 + tx];
  __syncthreads();
  for (int r = 0; r < 4; r++)
    vhT[(size_t)(b * DH_ + d0 + ty + 8*r) * S_ + s0 + tx] = tl[tx][ty + 8*r];
}

// ---------------- GEMM: C[M,N] = A[M,K](bf16) @ BT[N,K](bf16)^T + bias ----------------
template<int OUTF32>
__global__ __launch_bounds__(256) void gemm_bt(const u16* __restrict__ A,
    const u16* __restrict__ BT, const float* __restrict__ bias, void* __restrict__ Cv,
    int M, int N, int K)
{
  (void)M;
  __shared__ alignas(16) u16 Al[128 * 32];
  __shared__ alignas(16) u16 Bl[128 * 32];
  const int t = threadIdx.x, lane = t & 63, wave = t >> 6;
  const int quad = lane >> 4, lcol = lane & 15;
  const int m0 = blockIdx.y * 128, n0 = blockIdx.x * 128;
  const int wm = (wave >> 1) * 64, wn = (wave & 1) * 64;
  f32x4 acc[4][4] = {};
  for (int k0 = 0; k0 < K; k0 += 32) {
    for (int p = 0; p < 2; p++) {
      int c = p * 256 + wave * 64 + lane;      // 0..511 chunk id
      int row = c >> 2, kc = c & 3;            // row 0..127, 8-elem chunk 0..3
      stage16(A  + (size_t)(m0 + row) * K + k0 + kc * 8, Al + (p*256 + wave*64) * 8);
      stage16(BT + (size_t)(n0 + row) * K + k0 + kc * 8, Bl + (p*256 + wave*64) * 8);
    }
    __syncthreads();
    bf16x8 af[4], bfr[4];
    for (int i = 0; i < 4; i++)
      af[i]  = *(const bf16x8*)(Al + (wm + i*16 + lcol) * 32 + quad * 8);
    for (int j = 0; j < 4; j++)
      bfr[j] = *(const bf16x8*)(Bl + (wn + j*16 + lcol) * 32 + quad * 8);
    for (int i = 0; i < 4; i++)
      for (int j = 0; j < 4; j++)
        acc[i][j] = mfma16(af[i], bfr[j], acc[i][j]);
    __syncthreads();
  }
  for (int j = 0; j < 4; j++) {
    int n = n0 + wn + j * 16 + lcol;
    float bj = bias[n];
    for (int i = 0; i < 4; i++) {
      int mbase = m0 + wm + i * 16 + quad * 4;
      for (int r = 0; r < 4; r++) {
        float vv = acc[i][j][r] + bj;
        if (OUTF32) ((float*)Cv)[(size_t)(mbase + r) * N + n] = vv;
        else        ((u16*)Cv)  [(size_t)(mbase + r) * N + n] = f2bf(vv);
      }
    }
  }
}

// ---------------- Flash attention v5 ----------------
// v5 changes vs v4 (which measured 215us, MfmaUtil 29.6%, ~50% latency stall):
//   * KVBLK 32 -> 64: one barrier + one staging burst per 64 kv rows
//     (barrier events halve: 64 -> 32). LDS 64KB/block, 2 blocks/CU = 128KB.
//   * Inner compute = two register-neutral 32-kv sub-phases (pa/s/cc reused),
//     no barrier between them -> co-resident waves drift and braid pipes.
//   * T5: s_setprio(1) around MFMA clusters (m191: attn +4-7%).
// Kept from v4: in-register P via swapped QK^T + cvt_pk + permlane swaps,
// no-max softmax, l via ones-MFMA, global_load_lds staging with XOR swizzle.
__global__ __launch_bounds__(256, 2) void mqa_attn(const u16* __restrict__ qh,
    const u16* __restrict__ kh, const u16* __restrict__ vhT, u16* __restrict__ ao)
{
  __shared__ alignas(16) u16 Kl[2][64 * 128]; // [kv][dh], 16B-chunk swizzle st^(row&15)
  __shared__ alignas(16) u16 Vl[2][128 * 64]; // [dh][kv], 16B-chunk swizzle st^(row&7)
  const int t = threadIdx.x, lane = t & 63, wave = t >> 6;
  const int quad = lane >> 4, lcol = lane & 15;
  const int b = blockIdx.z, h = blockIdx.y;
  const int q0 = blockIdx.x * 256 + wave * 64;         // 64 rows per wave
  const float sc2 = 0.12751743f;             // (1/sqrt(128)) * log2(e)

  // Q fragments: 4 M-frags x 4 kk, persistent in registers (64 VGPR)
  bf16x8 qf[4][4];
  for (int m = 0; m < 4; m++) {
    const u16* qp = qh + (size_t)(b * S_ + q0 + m * 16 + lcol) * D_ + h * DH_ + quad * 8;
    for (int kk = 0; kk < 4; kk++) qf[m][kk] = *(const bf16x8*)(qp + kk * 32);
  }
  union { u16 u[8]; bf16x8 v; } one_u;
  for (int i = 0; i < 8; i++) one_u.u[i] = 0x3F80;
  const bf16x8 ones = one_u.v;

  f32x4 o[4][8] = {};
  f32x4 al[4] = {};
  const u16* kb = kh  + (size_t)b * S_ * DH_;
  const u16* vb = vhT + (size_t)b * DH_ * S_;

  // Stage 64-kv tile tt into buffer bi: K = 1024 16B chunks, V = 1024 chunks;
  // this wave covers chunks wave*64+lane + p*256, p=0..3.
  auto stageKV = [&](int tt, int bi) {
    int kv0 = tt * 64;
    for (int p = 0; p < 4; p++) {
      int c = p * 256 + wave * 64 + lane;      // 0..1023
      int row = c >> 4, st = c & 15;           // K row 0..63, chunk 0..15
      int kc = st ^ (row & 15);
      stage16(kb + (size_t)(kv0 + row) * DH_ + kc * 8, &Kl[bi][(p*256 + wave*64) * 8]);
    }
    for (int p = 0; p < 4; p++) {
      int c = p * 256 + wave * 64 + lane;      // 0..1023
      int row = c >> 3, st = c & 7;            // V row (dh) 0..127, chunk 0..7
      int kc = st ^ (row & 7);
      stage16(vb + (size_t)row * S_ + kv0 + kc * 8, &Vl[bi][(p*256 + wave*64) * 8]);
    }
  };

  stageKV(0, 0);
  for (int tt = 0; tt < S_ / 64; tt++) {
    const int bi = tt & 1;
    __syncthreads();                       // drains staging of tile tt; fences buf bi^1
    if (tt < S_ / 64 - 1) stageKV(tt + 1, bi ^ 1);   // in flight during compute

    const u16* Kb = &Kl[bi][0];
    const u16* Vb = &Vl[bi][0];

    // Two 32-kv sub-phases; registers (s, cc, pa) reused across ks.
    for (int ks = 0; ks < 2; ks++) {
      // S^T = K @ Q^T (swapped operands): per f, lane holds
      // S[kv = ks*32 + f*16 + quad*4 + r][q = lcol].
      unsigned cc[4][4];
      for (int f = 0; f < 2; f++) {
        f32x4 s[4] = {};
        const u16* kp = Kb + (size_t)(ks * 32 + f * 16 + lcol) * 128;  // row&15 == lcol
        __builtin_amdgcn_s_setprio(1);
        for (int kk = 0; kk < 4; kk++) {
          int swz = (kk * 4 + quad) ^ lcol;
          bf16x8 kfr = *(const bf16x8*)(kp + swz * 8);
          for (int m = 0; m < 4; m++)
            s[m] = mfma16(kfr, qf[m][kk], s[m]);
        }
        __builtin_amdgcn_s_setprio(0);
        for (int m = 0; m < 4; m++) {
          float e0 = exp2f(s[m][0] * sc2), e1 = exp2f(s[m][1] * sc2);
          float e2 = exp2f(s[m][2] * sc2), e3 = exp2f(s[m][3] * sc2);
          cc[m][f * 2 + 0] = pkbf(e0, e1);   // kv = ks*32 + f*16 + quad*4 + {0,1}
          cc[m][f * 2 + 1] = pkbf(e2, e3);   // kv = ks*32 + f*16 + quad*4 + {2,3}
        }
      }
      // Redistribute to PV A-frag layout: lane needs P[q=lcol][kv=ks*32+quad*8+j].
      bf16x8 pa[4];
      for (int m = 0; m < 4; m++) {
        asm("v_permlane32_swap_b32 %0, %1" : "+v"(cc[m][0]), "+v"(cc[m][2]));
        asm("v_permlane16_swap_b32 %0, %1" : "+v"(cc[m][0]), "+v"(cc[m][2]));
        asm("v_permlane32_swap_b32 %0, %1" : "+v"(cc[m][1]), "+v"(cc[m][3]));
        asm("v_permlane16_swap_b32 %0, %1" : "+v"(cc[m][1]), "+v"(cc[m][3]));
        union { unsigned u[4]; bf16x8 v; } pu;
        pu.u[0] = cc[m][0];   // kv ks*32 + quad*8 + {0,1}
        pu.u[1] = cc[m][1];   // kv ks*32 + quad*8 + {2,3}
        pu.u[2] = cc[m][2];   // kv ks*32 + quad*8 + {4,5}
        pu.u[3] = cc[m][3];   // kv ks*32 + quad*8 + {6,7}
        pa[m] = pu.v;
      }

      // O += P @ V (V-frag read feeds 4 MFMAs); V row = g*16+lcol, 8 chunks/row,
      // chunk = (ks*4+quad) ^ (row&7), row&7 == lcol&7.
      __builtin_amdgcn_s_setprio(1);
      for (int g = 0; g < 8; g++) {
        int kc = (ks * 4 + quad) ^ (lcol & 7);
        bf16x8 vfr = *(const bf16x8*)(Vb + (size_t)(g * 16 + lcol) * 64 + kc * 8);
        for (int m = 0; m < 4; m++)
          o[m][g] = mfma16(pa[m], vfr, o[m][g]);
      }
      // l += P @ 1
      for (int m = 0; m < 4; m++)
        al[m] = mfma16(pa[m], ones, al[m]);
      __builtin_amdgcn_s_setprio(0);
    }
  }

  // epilogue: normalize and store bf16, merged-head layout [B*S][D]
  for (int m = 0; m < 4; m++) {
    u16* op = ao + (size_t)(b * S_ + q0 + m * 16 + quad * 4) * D_ + h * DH_ + lcol;
    for (int r = 0; r < 4; r++) {
      float inv = 1.0f / al[m][r];
      for (int g = 0; g < 8; g++)
        op[(size_t)r * D_ + g * 16] = f2bf(o[m][g][r] * inv);
    }
  }
}

extern "C" void kernel_launch(void* const* d_in, const int* in_sizes, int n_in,
                              void* d_out, int out_size, void* d_ws, size_t ws_size,
                              hipStream_t stream)
{
  (void)in_sizes; (void)n_in; (void)out_size;
  const float* q  = (const float*)d_in[0];
  const float* k  = (const float*)d_in[1];
  const float* v  = (const float*)d_in[2];
  const float* Wq = (const float*)d_in[3];
  const float* bq = (const float*)d_in[4];
  const float* Wk = (const float*)d_in[5];
  const float* bk = (const float*)d_in[6];
  const float* Wv = (const float*)d_in[7];
  const float* bv = (const float*)d_in[8];
  const float* Wo = (const float*)d_in[9];
  const float* bo = (const float*)d_in[10];
  float* out = (float*)d_out;

  char* ws = (char*)d_ws;
  size_t off = 0;
  auto alloc = [&](size_t bytes) -> char* {
    char* p = ws + off; off += (bytes + 255) & ~(size_t)255; return p;
  };
  u16* xbf = (u16*)alloc((size_t)M_ * D_ * 2);    // cast buffer k->v->q, later ao
  u16* qh  = (u16*)alloc((size_t)M_ * D_ * 2);
  u16* kh  = (u16*)alloc((size_t)M_ * DH_ * 2);
  u16* vh  = (u16*)alloc((size_t)M_ * DH_ * 2);
  u16* vhT = (u16*)alloc((size_t)M_ * DH_ * 2);
  u16* WqT = (u16*)alloc((size_t)D_ * D_ * 2);
  u16* WkT = (u16*)alloc((size_t)DH_ * D_ * 2);
  u16* WvT = (u16*)alloc((size_t)DH_ * D_ * 2);
  u16* WoT = (u16*)alloc((size_t)D_ * D_ * 2);
  u16* ao  = xbf;   // xbf dead after Q-proj GEMM

  if (off > ws_size) return;  // diagnosable failure instead of OOB fault

  const int n4 = M_ * D_ / 4;

  transpose_bf<<<dim3(D_/32,  D_/32), dim3(32, 8), 0, stream>>>(Wq, WqT, D_, D_);
  transpose_bf<<<dim3(DH_/32, D_/32), dim3(32, 8), 0, stream>>>(Wk, WkT, D_, DH_);
  transpose_bf<<<dim3(DH_/32, D_/32), dim3(32, 8), 0, stream>>>(Wv, WvT, D_, DH_);
  transpose_bf<<<dim3(D_/32,  D_/32), dim3(32, 8), 0, stream>>>(Wo, WoT, D_, D_);

  // K projection
  cvt_bf16<<<dim3(n4 / 256), dim3(256), 0, stream>>>(k, xbf, n4);
  gemm_bt<0><<<dim3(DH_/128, M_/128), dim3(256), 0, stream>>>(xbf, WkT, bk, kh, M_, DH_, D_);
  // V projection (+ transpose to [B][DH][S])
  cvt_bf16<<<dim3(n4 / 256), dim3(256), 0, stream>>>(v, xbf, n4);
  gemm_bt<0><<<dim3(DH_/128, M_/128), dim3(256), 0, stream>>>(xbf, WvT, bv, vh, M_, DH_, D_);
  transpose_vh<<<dim3(DH_/32, S_/32, B_), dim3(32, 8), 0, stream>>>(vh, vhT);
  // Q projection
  cvt_bf16<<<dim3(n4 / 256), dim3(256), 0, stream>>>(q, xbf, n4);
  gemm_bt<0><<<dim3(D_/128,  M_/128), dim3(256), 0, stream>>>(xbf, WqT, bq, qh, M_, D_, D_);

  // Attention (writes ao == xbf, merged heads)
  mqa_attn<<<dim3(S_/256, H_, B_), dim3(256), 0, stream>>>(qh, kh, vhT, ao);

  // Output projection (fp32 out + bias)
  gemm_bt<1><<<dim3(D_/128, M_/128), dim3(256), 0, stream>>>(ao, WoT, bo, out, M_, D_, D_);
}

// Round 4
// 741.973 us; speedup vs baseline: 1.0938x; 1.0938x over previous
//
#include <hip/hip_runtime.h>
#include <stdint.h>

#define B_  4
#define S_  2048
#define D_  2048
#define H_  16
#define DH_ 128
#define M_  (B_*S_)

typedef unsigned short u16;
typedef __bf16 bf16x8 __attribute__((ext_vector_type(8)));
typedef float  f32x4  __attribute__((ext_vector_type(4)));
typedef u16    u16x4  __attribute__((ext_vector_type(4)));

__device__ __forceinline__ u16 f2bf(float f){
  unsigned x = __float_as_uint(f);
  x += 0x7fffu + ((x >> 16) & 1u);          // RNE
  return (u16)(x >> 16);
}

// v_cvt_pk_bf16_f32: D[15:0]=bf16(lo), D[31:16]=bf16(hi). No HIP builtin (m240).
__device__ __forceinline__ unsigned pkbf(float lo, float hi){
  unsigned r;
  asm("v_cvt_pk_bf16_f32 %0, %1, %2" : "=v"(r) : "v"(lo), "v"(hi));
  return r;
}

// Async global->LDS, 16B per lane. LDS dest = wave-uniform base + lane*16.
__device__ __forceinline__ void stage16(const void* g, void* lds_base){
  __builtin_amdgcn_global_load_lds(
      (const __attribute__((address_space(1))) void*)g,
      (__attribute__((address_space(3))) void*)lds_base, 16, 0, 0);
}

__device__ __forceinline__ f32x4 mfma16(bf16x8 a, bf16x8 b, f32x4 c){
  return __builtin_amdgcn_mfma_f32_16x16x32_bf16(a, b, c, 0, 0, 0);
}

// ---------------- fp32 -> bf16 cast (vectorized) ----------------
__global__ void cvt_bf16(const float* __restrict__ s, u16* __restrict__ d, int n4){
  int i = blockIdx.x * 256 + threadIdx.x;
  if (i >= n4) return;
  float4 f = ((const float4*)s)[i];
  u16x4 u = { f2bf(f.x), f2bf(f.y), f2bf(f.z), f2bf(f.w) };
  ((u16x4*)d)[i] = u;
}

// ---------------- W [K][N] fp32 -> WT [N][K] bf16 ----------------
__global__ void transpose_bf(const float* __restrict__ W, u16* __restrict__ WT, int K, int N){
  __shared__ float tl[32][33];
  int n0 = blockIdx.x * 32, k0 = blockIdx.y * 32;
  int tx = threadIdx.x, ty = threadIdx.y;     // block (32,8)
  for (int r = 0; r < 4; r++)
    tl[ty + 8*r][tx] = W[(size_t)(k0 + ty + 8*r) * N + n0 + tx];
  __syncthreads();
  for (int r = 0; r < 4; r++)
    WT[(size_t)(n0 + ty + 8*r) * K + k0 + tx] = f2bf(tl[tx][ty + 8*r]);
}

// -------- vh [B*S][DH] bf16 -> vhT [B][DH][S] bf16 --------
__global__ void transpose_vh(const u16* __restrict__ vh, u16* __restrict__ vhT){
  __shared__ u16 tl[32][33];
  int b = blockIdx.z, d0 = blockIdx.x * 32, s0 = blockIdx.y * 32;
  int tx = threadIdx.x, ty = threadIdx.y;     // block (32,8)
  for (int r = 0; r < 4; r++)
    tl[ty + 8*r][tx] = vh[(size_t)(b * S_ + s0 + ty + 8*r) * DH_ + d0 + tx];
  __syncthreads();
  for (int r = 0; r < 4; r++)
    vhT[(size_t)(b * DH_ + d0 + ty + 8*r) * S_ + s0 + tx] = tl[tx][ty + 8*r];
}

// ---------------- GEMM: C[M,N] = A[M,K](bf16) @ BT[N,K](bf16)^T + bias ----------------
template<int OUTF32>
__global__ __launch_bounds__(256) void gemm_bt(const u16* __restrict__ A,
    const u16* __restrict__ BT, const float* __restrict__ bias, void* __restrict__ Cv,
    int M, int N, int K)
{
  (void)M;
  __shared__ alignas(16) u16 Al[128 * 32];
  __shared__ alignas(16) u16 Bl[128 * 32];
  const int t = threadIdx.x, lane = t & 63, wave = t >> 6;
  const int quad = lane >> 4, lcol = lane & 15;
  const int m0 = blockIdx.y * 128, n0 = blockIdx.x * 128;
  const int wm = (wave >> 1) * 64, wn = (wave & 1) * 64;
  f32x4 acc[4][4] = {};
  for (int k0 = 0; k0 < K; k0 += 32) {
    for (int p = 0; p < 2; p++) {
      int c = p * 256 + wave * 64 + lane;      // 0..511 chunk id
      int row = c >> 2, kc = c & 3;            // row 0..127, 8-elem chunk 0..3
      stage16(A  + (size_t)(m0 + row) * K + k0 + kc * 8, Al + (p*256 + wave*64) * 8);
      stage16(BT + (size_t)(n0 + row) * K + k0 + kc * 8, Bl + (p*256 + wave*64) * 8);
    }
    __syncthreads();
    bf16x8 af[4], bfr[4];
    for (int i = 0; i < 4; i++)
      af[i]  = *(const bf16x8*)(Al + (wm + i*16 + lcol) * 32 + quad * 8);
    for (int j = 0; j < 4; j++)
      bfr[j] = *(const bf16x8*)(Bl + (wn + j*16 + lcol) * 32 + quad * 8);
    for (int i = 0; i < 4; i++)
      for (int j = 0; j < 4; j++)
        acc[i][j] = mfma16(af[i], bfr[j], acc[i][j]);
    __syncthreads();
  }
  for (int j = 0; j < 4; j++) {
    int n = n0 + wn + j * 16 + lcol;
    float bj = bias[n];
    for (int i = 0; i < 4; i++) {
      int mbase = m0 + wm + i * 16 + quad * 4;
      for (int r = 0; r < 4; r++) {
        float vv = acc[i][j][r] + bj;
        if (OUTF32) ((float*)Cv)[(size_t)(mbase + r) * N + n] = vv;
        else        ((u16*)Cv)  [(size_t)(mbase + r) * N + n] = f2bf(vv);
      }
    }
  }
}

// ---------------- Flash attention v6 ----------------
// v6 = v4 structure (KVBLK=32, known 215us) with per-wave state HALVED to
// raise occupancy: 32 q-rows/wave (2 M-frags), qf 64->32 VGPR, o 128->64 acc,
// al 16->8 acc (~272 -> ~160 regs/wave), __launch_bounds__(256,3) -> 3
// waves/SIMD (was 2). Grid x doubles (1024 blocks): natural block stagger.
// v5's KVBLK=64 + ks-loop REGRESSED (273us, WRITE_SIZE 84->212MB = suspected
// scratch spill from longer live ranges) -- reverted entirely.
// Kept: in-register P (swapped QK^T + cvt_pk + permlane), no-max softmax,
// l via ones-MFMA, double-buffered global_load_lds staging, setprio (m191).
__global__ __launch_bounds__(256, 3) void mqa_attn(const u16* __restrict__ qh,
    const u16* __restrict__ kh, const u16* __restrict__ vhT, u16* __restrict__ ao)
{
  __shared__ alignas(16) u16 Kl[2][32 * 128]; // [kv][dh], 16B-chunk swizzle st^(row&15)
  __shared__ alignas(16) u16 Vl[2][128 * 32]; // [dh][kv], swizzle st^(row&3)^((row>>2)&3)
  const int t = threadIdx.x, lane = t & 63, wave = t >> 6;
  const int quad = lane >> 4, lcol = lane & 15;
  const int b = blockIdx.z, h = blockIdx.y;
  const int q0 = blockIdx.x * 128 + wave * 32;         // 32 rows per wave
  const float sc2 = 0.12751743f;             // (1/sqrt(128)) * log2(e)

  // Q fragments: 2 M-frags x 4 kk, persistent in registers (32 VGPR)
  bf16x8 qf[2][4];
  for (int m = 0; m < 2; m++) {
    const u16* qp = qh + (size_t)(b * S_ + q0 + m * 16 + lcol) * D_ + h * DH_ + quad * 8;
    for (int kk = 0; kk < 4; kk++) qf[m][kk] = *(const bf16x8*)(qp + kk * 32);
  }
  union { u16 u[8]; bf16x8 v; } one_u;
  for (int i = 0; i < 8; i++) one_u.u[i] = 0x3F80;
  const bf16x8 ones = one_u.v;

  f32x4 o[2][8] = {};
  f32x4 al[2] = {};
  const u16* kb = kh  + (size_t)b * S_ * DH_;
  const u16* vb = vhT + (size_t)b * DH_ * S_;

  // Stage tile tt (kv0 = tt*32) into buffer bi: K 512 chunks + V 512 chunks,
  // this wave covers chunks wave*64+lane + p*256.
  auto stageKV = [&](int tt, int bi) {
    int kv0 = tt * 32;
    for (int p = 0; p < 2; p++) {
      int c = p * 256 + wave * 64 + lane;
      int row = c >> 4, st = c & 15;
      int kc = st ^ (row & 15);
      stage16(kb + (size_t)(kv0 + row) * DH_ + kc * 8, &Kl[bi][(p*256 + wave*64) * 8]);
    }
    for (int p = 0; p < 2; p++) {
      int c = p * 256 + wave * 64 + lane;
      int row = c >> 2, st = c & 3;
      int kc = st ^ (row & 3) ^ ((row >> 2) & 3);
      stage16(vb + (size_t)row * S_ + kv0 + kc * 8, &Vl[bi][(p*256 + wave*64) * 8]);
    }
  };

  stageKV(0, 0);
  for (int tt = 0; tt < S_ / 32; tt++) {
    const int bi = tt & 1;
    __syncthreads();                       // drains staging of tile tt; fences buf bi^1
    if (tt < S_ / 32 - 1) stageKV(tt + 1, bi ^ 1);   // in flight during compute

    const u16* Kb = &Kl[bi][0];
    const u16* Vb = &Vl[bi][0];

    // S^T = K @ Q^T (swapped operands): per kvf, lane holds S[kv=quad*4+r][q=lcol]
    // cc[m][.] collects packed bf16 pairs: [0,1] from kvf0, [2,3] from kvf1
    unsigned cc[2][4];
    for (int kvf = 0; kvf < 2; kvf++) {
      f32x4 s[2] = {};
      const u16* kp = Kb + (size_t)(kvf * 16 + lcol) * 128;   // row&15 == lcol
      __builtin_amdgcn_s_setprio(1);
      for (int kk = 0; kk < 4; kk++) {
        int swz = (kk * 4 + quad) ^ lcol;
        bf16x8 kfr = *(const bf16x8*)(kp + swz * 8);
        for (int m = 0; m < 2; m++)
          s[m] = mfma16(kfr, qf[m][kk], s[m]);
      }
      __builtin_amdgcn_s_setprio(0);
      for (int m = 0; m < 2; m++) {
        float e0 = exp2f(s[m][0] * sc2), e1 = exp2f(s[m][1] * sc2);
        float e2 = exp2f(s[m][2] * sc2), e3 = exp2f(s[m][3] * sc2);
        cc[m][kvf * 2 + 0] = pkbf(e0, e1);   // kv = quad*4 + {0,1} (+16*kvf)
        cc[m][kvf * 2 + 1] = pkbf(e2, e3);   // kv = quad*4 + {2,3} (+16*kvf)
      }
    }
    // Redistribute to PV A-frag layout: lane needs P[q=lcol][kv=quad*8+j].
    bf16x8 pa[2];
    for (int m = 0; m < 2; m++) {
      asm("v_permlane32_swap_b32 %0, %1" : "+v"(cc[m][0]), "+v"(cc[m][2]));
      asm("v_permlane16_swap_b32 %0, %1" : "+v"(cc[m][0]), "+v"(cc[m][2]));
      asm("v_permlane32_swap_b32 %0, %1" : "+v"(cc[m][1]), "+v"(cc[m][3]));
      asm("v_permlane16_swap_b32 %0, %1" : "+v"(cc[m][1]), "+v"(cc[m][3]));
      union { unsigned u[4]; bf16x8 v; } pu;
      pu.u[0] = cc[m][0];   // kv quad*8+{0,1}
      pu.u[1] = cc[m][1];   // kv quad*8+{2,3}
      pu.u[2] = cc[m][2];   // kv quad*8+{4,5}
      pu.u[3] = cc[m][3];   // kv quad*8+{6,7}
      pa[m] = pu.v;
    }

    // O += P @ V (V-frag read feeds 2 MFMAs)
    __builtin_amdgcn_s_setprio(1);
    for (int g = 0; g < 8; g++) {
      int swz = quad ^ (lcol & 3) ^ ((lcol >> 2) & 3);  // row = g*16+lcol
      bf16x8 vfr = *(const bf16x8*)(Vb + (size_t)(g * 16 + lcol) * 32 + swz * 8);
      for (int m = 0; m < 2; m++)
        o[m][g] = mfma16(pa[m], vfr, o[m][g]);
    }
    // l += P @ 1
    for (int m = 0; m < 2; m++)
      al[m] = mfma16(pa[m], ones, al[m]);
    __builtin_amdgcn_s_setprio(0);
  }

  // epilogue: normalize and store bf16, merged-head layout [B*S][D]
  for (int m = 0; m < 2; m++) {
    u16* op = ao + (size_t)(b * S_ + q0 + m * 16 + quad * 4) * D_ + h * DH_ + lcol;
    for (int r = 0; r < 4; r++) {
      float inv = 1.0f / al[m][r];
      for (int g = 0; g < 8; g++)
        op[(size_t)r * D_ + g * 16] = f2bf(o[m][g][r] * inv);
    }
  }
}

extern "C" void kernel_launch(void* const* d_in, const int* in_sizes, int n_in,
                              void* d_out, int out_size, void* d_ws, size_t ws_size,
                              hipStream_t stream)
{
  (void)in_sizes; (void)n_in; (void)out_size;
  const float* q  = (const float*)d_in[0];
  const float* k  = (const float*)d_in[1];
  const float* v  = (const float*)d_in[2];
  const float* Wq = (const float*)d_in[3];
  const float* bq = (const float*)d_in[4];
  const float* Wk = (const float*)d_in[5];
  const float* bk = (const float*)d_in[6];
  const float* Wv = (const float*)d_in[7];
  const float* bv = (const float*)d_in[8];
  const float* Wo = (const float*)d_in[9];
  const float* bo = (const float*)d_in[10];
  float* out = (float*)d_out;

  char* ws = (char*)d_ws;
  size_t off = 0;
  auto alloc = [&](size_t bytes) -> char* {
    char* p = ws + off; off += (bytes + 255) & ~(size_t)255; return p;
  };
  u16* xbf = (u16*)alloc((size_t)M_ * D_ * 2);    // cast buffer k->v->q, later ao
  u16* qh  = (u16*)alloc((size_t)M_ * D_ * 2);
  u16* kh  = (u16*)alloc((size_t)M_ * DH_ * 2);
  u16* vh  = (u16*)alloc((size_t)M_ * DH_ * 2);
  u16* vhT = (u16*)alloc((size_t)M_ * DH_ * 2);
  u16* WqT = (u16*)alloc((size_t)D_ * D_ * 2);
  u16* WkT = (u16*)alloc((size_t)DH_ * D_ * 2);
  u16* WvT = (u16*)alloc((size_t)DH_ * D_ * 2);
  u16* WoT = (u16*)alloc((size_t)D_ * D_ * 2);
  u16* ao  = xbf;   // xbf dead after Q-proj GEMM

  if (off > ws_size) return;  // diagnosable failure instead of OOB fault

  const int n4 = M_ * D_ / 4;

  transpose_bf<<<dim3(D_/32,  D_/32), dim3(32, 8), 0, stream>>>(Wq, WqT, D_, D_);
  transpose_bf<<<dim3(DH_/32, D_/32), dim3(32, 8), 0, stream>>>(Wk, WkT, D_, DH_);
  transpose_bf<<<dim3(DH_/32, D_/32), dim3(32, 8), 0, stream>>>(Wv, WvT, D_, DH_);
  transpose_bf<<<dim3(D_/32,  D_/32), dim3(32, 8), 0, stream>>>(Wo, WoT, D_, D_);

  // K projection
  cvt_bf16<<<dim3(n4 / 256), dim3(256), 0, stream>>>(k, xbf, n4);
  gemm_bt<0><<<dim3(DH_/128, M_/128), dim3(256), 0, stream>>>(xbf, WkT, bk, kh, M_, DH_, D_);
  // V projection (+ transpose to [B][DH][S])
  cvt_bf16<<<dim3(n4 / 256), dim3(256), 0, stream>>>(v, xbf, n4);
  gemm_bt<0><<<dim3(DH_/128, M_/128), dim3(256), 0, stream>>>(xbf, WvT, bv, vh, M_, DH_, D_);
  transpose_vh<<<dim3(DH_/32, S_/32, B_), dim3(32, 8), 0, stream>>>(vh, vhT);
  // Q projection
  cvt_bf16<<<dim3(n4 / 256), dim3(256), 0, stream>>>(q, xbf, n4);
  gemm_bt<0><<<dim3(D_/128,  M_/128), dim3(256), 0, stream>>>(xbf, WqT, bq, qh, M_, D_, D_);

  // Attention (writes ao == xbf, merged heads)
  mqa_attn<<<dim3(S_/128, H_, B_), dim3(256), 0, stream>>>(qh, kh, vhT, ao);

  // Output projection (fp32 out + bias)
  gemm_bt<1><<<dim3(D_/128, M_/128), dim3(256), 0, stream>>>(ao, WoT, bo, out, M_, D_, D_);
}

// Round 5
// 684.473 us; speedup vs baseline: 1.1857x; 1.0840x over previous
//
#include <hip/hip_runtime.h>
#include <stdint.h>

#define B_  4
#define S_  2048
#define D_  2048
#define H_  16
#define DH_ 128
#define M_  (B_*S_)

typedef unsigned short u16;
typedef __bf16 bf16x8 __attribute__((ext_vector_type(8)));
typedef float  f32x4  __attribute__((ext_vector_type(4)));
typedef u16    u16x4  __attribute__((ext_vector_type(4)));

__device__ __forceinline__ u16 f2bf(float f){
  unsigned x = __float_as_uint(f);
  x += 0x7fffu + ((x >> 16) & 1u);          // RNE
  return (u16)(x >> 16);
}

// v_cvt_pk_bf16_f32: D[15:0]=bf16(lo), D[31:16]=bf16(hi). No HIP builtin (m240).
__device__ __forceinline__ unsigned pkbf(float lo, float hi){
  unsigned r;
  asm("v_cvt_pk_bf16_f32 %0, %1, %2" : "=v"(r) : "v"(lo), "v"(hi));
  return r;
}

// Async global->LDS, 16B per lane. LDS dest = wave-uniform base + lane*16.
__device__ __forceinline__ void stage16(const void* g, void* lds_base){
  __builtin_amdgcn_global_load_lds(
      (const __attribute__((address_space(1))) void*)g,
      (__attribute__((address_space(3))) void*)lds_base, 16, 0, 0);
}

__device__ __forceinline__ f32x4 mfma16(bf16x8 a, bf16x8 b, f32x4 c){
  return __builtin_amdgcn_mfma_f32_16x16x32_bf16(a, b, c, 0, 0, 0);
}

// ---------------- fp32 -> bf16 cast (vectorized) ----------------
__global__ void cvt_bf16(const float* __restrict__ s, u16* __restrict__ d, int n4){
  int i = blockIdx.x * 256 + threadIdx.x;
  if (i >= n4) return;
  float4 f = ((const float4*)s)[i];
  u16x4 u = { f2bf(f.x), f2bf(f.y), f2bf(f.z), f2bf(f.w) };
  ((u16x4*)d)[i] = u;
}

// Fused dual cast: blockIdx.y selects (s0->d0) or (s1->d1).
__global__ void cvt_bf16_2(const float* __restrict__ s0, const float* __restrict__ s1,
                           u16* __restrict__ d0, u16* __restrict__ d1, int n4){
  const float* s = blockIdx.y ? s1 : s0;
  u16*        d = blockIdx.y ? d1 : d0;
  int i = blockIdx.x * 256 + threadIdx.x;
  if (i >= n4) return;
  float4 f = ((const float4*)s)[i];
  u16x4 u = { f2bf(f.x), f2bf(f.y), f2bf(f.z), f2bf(f.w) };
  ((u16x4*)d)[i] = u;
}

// ---------------- W [K][N] fp32 -> WT [N][K] bf16 ----------------
__global__ void transpose_bf(const float* __restrict__ W, u16* __restrict__ WT, int K, int N){
  __shared__ float tl[32][33];
  int n0 = blockIdx.x * 32, k0 = blockIdx.y * 32;
  int tx = threadIdx.x, ty = threadIdx.y;     // block (32,8)
  for (int r = 0; r < 4; r++)
    tl[ty + 8*r][tx] = W[(size_t)(k0 + ty + 8*r) * N + n0 + tx];
  __syncthreads();
  for (int r = 0; r < 4; r++)
    WT[(size_t)(n0 + ty + 8*r) * K + k0 + tx] = f2bf(tl[tx][ty + 8*r]);
}

// -------- vh [B*S][DH] bf16 -> vhT [B][DH][S] bf16 --------
__global__ void transpose_vh(const u16* __restrict__ vh, u16* __restrict__ vhT){
  __shared__ u16 tl[32][33];
  int b = blockIdx.z, d0 = blockIdx.x * 32, s0 = blockIdx.y * 32;
  int tx = threadIdx.x, ty = threadIdx.y;     // block (32,8)
  for (int r = 0; r < 4; r++)
    tl[ty + 8*r][tx] = vh[(size_t)(b * S_ + s0 + ty + 8*r) * DH_ + d0 + tx];
  __syncthreads();
  for (int r = 0; r < 4; r++)
    vhT[(size_t)(b * DH_ + d0 + ty + 8*r) * S_ + s0 + tx] = tl[tx][ty + 8*r];
}

// ---------------- GEMM: C[M,N] = A[M,K](bf16) @ BT[N,K](bf16)^T + bias ----------------
template<int OUTF32>
__global__ __launch_bounds__(256) void gemm_bt(const u16* __restrict__ A,
    const u16* __restrict__ BT, const float* __restrict__ bias, void* __restrict__ Cv,
    int M, int N, int K)
{
  (void)M;
  __shared__ alignas(16) u16 Al[128 * 32];
  __shared__ alignas(16) u16 Bl[128 * 32];
  const int t = threadIdx.x, lane = t & 63, wave = t >> 6;
  const int quad = lane >> 4, lcol = lane & 15;
  const int m0 = blockIdx.y * 128, n0 = blockIdx.x * 128;
  const int wm = (wave >> 1) * 64, wn = (wave & 1) * 64;
  f32x4 acc[4][4] = {};
  for (int k0 = 0; k0 < K; k0 += 32) {
    for (int p = 0; p < 2; p++) {
      int c = p * 256 + wave * 64 + lane;      // 0..511 chunk id
      int row = c >> 2, kc = c & 3;            // row 0..127, 8-elem chunk 0..3
      stage16(A  + (size_t)(m0 + row) * K + k0 + kc * 8, Al + (p*256 + wave*64) * 8);
      stage16(BT + (size_t)(n0 + row) * K + k0 + kc * 8, Bl + (p*256 + wave*64) * 8);
    }
    __syncthreads();
    bf16x8 af[4], bfr[4];
    for (int i = 0; i < 4; i++)
      af[i]  = *(const bf16x8*)(Al + (wm + i*16 + lcol) * 32 + quad * 8);
    for (int j = 0; j < 4; j++)
      bfr[j] = *(const bf16x8*)(Bl + (wn + j*16 + lcol) * 32 + quad * 8);
    for (int i = 0; i < 4; i++)
      for (int j = 0; j < 4; j++)
        acc[i][j] = mfma16(af[i], bfr[j], acc[i][j]);
    __syncthreads();
  }
  for (int j = 0; j < 4; j++) {
    int n = n0 + wn + j * 16 + lcol;
    float bj = bias[n];
    for (int i = 0; i < 4; i++) {
      int mbase = m0 + wm + i * 16 + quad * 4;
      for (int r = 0; r < 4; r++) {
        float vv = acc[i][j][r] + bj;
        if (OUTF32) ((float*)Cv)[(size_t)(mbase + r) * N + n] = vv;
        else        ((u16*)Cv)  [(size_t)(mbase + r) * N + n] = f2bf(vv);
      }
    }
  }
}

// -------- Fused K/V projection: C[M,128] = A[M,2048] @ BT[128,2048]^T + bias --------
// 32x128 tile, grid (M/32, 1, 2); blockIdx.z selects the K- or V-projection
// operand set. 512 blocks total (vs 64+64 with 128x128 tiles): full CU
// coverage, both projections latency-overlap in one dispatch.
__global__ __launch_bounds__(256) void gemm_kv(
    const u16* __restrict__ A0, const u16* __restrict__ A1,
    const u16* __restrict__ BT0, const u16* __restrict__ BT1,
    const float* __restrict__ b0, const float* __restrict__ b1,
    u16* __restrict__ C0, u16* __restrict__ C1)
{
  const int sel = blockIdx.z;
  const u16* A  = sel ? A1 : A0;
  const u16* BT = sel ? BT1 : BT0;
  const float* bias = sel ? b1 : b0;
  u16* C = sel ? C1 : C0;

  __shared__ alignas(16) u16 Al[32 * 32];    // 2 KB
  __shared__ alignas(16) u16 Bl[128 * 32];   // 8 KB
  const int t = threadIdx.x, lane = t & 63, wave = t >> 6;
  const int quad = lane >> 4, lcol = lane & 15;
  const int m0 = blockIdx.x * 32;

  f32x4 acc[2][2] = {};
  for (int k0 = 0; k0 < D_; k0 += 32) {
    // A: 128 chunks (waves 0,1) | B rows 0..63 (waves 2,3)
    if (t < 128) {
      int row = t >> 2, kc = t & 3;
      stage16(A + (size_t)(m0 + row) * D_ + k0 + kc * 8, Al + (wave * 64) * 8);
    } else {
      int bc = t - 128, row = bc >> 2, kc = bc & 3;
      stage16(BT + (size_t)row * D_ + k0 + kc * 8, Bl + ((wave - 2) * 64) * 8);
    }
    // B rows 32..95 (all 4 waves)
    {
      int bc = t + 128, row = bc >> 2, kc = bc & 3;
      stage16(BT + (size_t)row * D_ + k0 + kc * 8, Bl + (128 + wave * 64) * 8);
    }
    // B rows 96..127 (waves 0,1)
    if (t < 128) {
      int bc = t + 384, row = bc >> 2, kc = bc & 3;
      stage16(BT + (size_t)row * D_ + k0 + kc * 8, Bl + (384 + wave * 64) * 8);
    }
    __syncthreads();
    bf16x8 af[2], bfr[2];
    for (int i = 0; i < 2; i++)
      af[i]  = *(const bf16x8*)(Al + (i*16 + lcol) * 32 + quad * 8);
    for (int j = 0; j < 2; j++)
      bfr[j] = *(const bf16x8*)(Bl + (wave*32 + j*16 + lcol) * 32 + quad * 8);
    for (int i = 0; i < 2; i++)
      for (int j = 0; j < 2; j++)
        acc[i][j] = mfma16(af[i], bfr[j], acc[i][j]);
    __syncthreads();
  }
  for (int j = 0; j < 2; j++) {
    int n = wave * 32 + j * 16 + lcol;
    float bj = bias[n];
    for (int i = 0; i < 2; i++) {
      int mbase = m0 + i * 16 + quad * 4;
      for (int r = 0; r < 4; r++)
        C[(size_t)(mbase + r) * DH_ + n] = f2bf(acc[i][j][r] + bj);
    }
  }
}

// ---------------- Flash attention v6 (unchanged from round-4 best: 197us) -------
// 32 q-rows/wave (2 M-frags), KVBLK=32 double-buffered, in-register P via
// swapped QK^T + cvt_pk + permlane swaps, no-max softmax, l via ones-MFMA,
// __launch_bounds__(256,3): ~140 unified regs -> 3 waves/SIMD.
__global__ __launch_bounds__(256, 3) void mqa_attn(const u16* __restrict__ qh,
    const u16* __restrict__ kh, const u16* __restrict__ vhT, u16* __restrict__ ao)
{
  __shared__ alignas(16) u16 Kl[2][32 * 128]; // [kv][dh], 16B-chunk swizzle st^(row&15)
  __shared__ alignas(16) u16 Vl[2][128 * 32]; // [dh][kv], swizzle st^(row&3)^((row>>2)&3)
  const int t = threadIdx.x, lane = t & 63, wave = t >> 6;
  const int quad = lane >> 4, lcol = lane & 15;
  const int b = blockIdx.z, h = blockIdx.y;
  const int q0 = blockIdx.x * 128 + wave * 32;         // 32 rows per wave
  const float sc2 = 0.12751743f;             // (1/sqrt(128)) * log2(e)

  bf16x8 qf[2][4];
  for (int m = 0; m < 2; m++) {
    const u16* qp = qh + (size_t)(b * S_ + q0 + m * 16 + lcol) * D_ + h * DH_ + quad * 8;
    for (int kk = 0; kk < 4; kk++) qf[m][kk] = *(const bf16x8*)(qp + kk * 32);
  }
  union { u16 u[8]; bf16x8 v; } one_u;
  for (int i = 0; i < 8; i++) one_u.u[i] = 0x3F80;
  const bf16x8 ones = one_u.v;

  f32x4 o[2][8] = {};
  f32x4 al[2] = {};
  const u16* kb = kh  + (size_t)b * S_ * DH_;
  const u16* vb = vhT + (size_t)b * DH_ * S_;

  auto stageKV = [&](int tt, int bi) {
    int kv0 = tt * 32;
    for (int p = 0; p < 2; p++) {
      int c = p * 256 + wave * 64 + lane;
      int row = c >> 4, st = c & 15;
      int kc = st ^ (row & 15);
      stage16(kb + (size_t)(kv0 + row) * DH_ + kc * 8, &Kl[bi][(p*256 + wave*64) * 8]);
    }
    for (int p = 0; p < 2; p++) {
      int c = p * 256 + wave * 64 + lane;
      int row = c >> 2, st = c & 3;
      int kc = st ^ (row & 3) ^ ((row >> 2) & 3);
      stage16(vb + (size_t)row * S_ + kv0 + kc * 8, &Vl[bi][(p*256 + wave*64) * 8]);
    }
  };

  stageKV(0, 0);
  for (int tt = 0; tt < S_ / 32; tt++) {
    const int bi = tt & 1;
    __syncthreads();                       // drains staging of tile tt; fences buf bi^1
    if (tt < S_ / 32 - 1) stageKV(tt + 1, bi ^ 1);   // in flight during compute

    const u16* Kb = &Kl[bi][0];
    const u16* Vb = &Vl[bi][0];

    unsigned cc[2][4];
    for (int kvf = 0; kvf < 2; kvf++) {
      f32x4 s[2] = {};
      const u16* kp = Kb + (size_t)(kvf * 16 + lcol) * 128;   // row&15 == lcol
      __builtin_amdgcn_s_setprio(1);
      for (int kk = 0; kk < 4; kk++) {
        int swz = (kk * 4 + quad) ^ lcol;
        bf16x8 kfr = *(const bf16x8*)(kp + swz * 8);
        for (int m = 0; m < 2; m++)
          s[m] = mfma16(kfr, qf[m][kk], s[m]);
      }
      __builtin_amdgcn_s_setprio(0);
      for (int m = 0; m < 2; m++) {
        float e0 = exp2f(s[m][0] * sc2), e1 = exp2f(s[m][1] * sc2);
        float e2 = exp2f(s[m][2] * sc2), e3 = exp2f(s[m][3] * sc2);
        cc[m][kvf * 2 + 0] = pkbf(e0, e1);
        cc[m][kvf * 2 + 1] = pkbf(e2, e3);
      }
    }
    bf16x8 pa[2];
    for (int m = 0; m < 2; m++) {
      asm("v_permlane32_swap_b32 %0, %1" : "+v"(cc[m][0]), "+v"(cc[m][2]));
      asm("v_permlane16_swap_b32 %0, %1" : "+v"(cc[m][0]), "+v"(cc[m][2]));
      asm("v_permlane32_swap_b32 %0, %1" : "+v"(cc[m][1]), "+v"(cc[m][3]));
      asm("v_permlane16_swap_b32 %0, %1" : "+v"(cc[m][1]), "+v"(cc[m][3]));
      union { unsigned u[4]; bf16x8 v; } pu;
      pu.u[0] = cc[m][0];
      pu.u[1] = cc[m][1];
      pu.u[2] = cc[m][2];
      pu.u[3] = cc[m][3];
      pa[m] = pu.v;
    }

    __builtin_amdgcn_s_setprio(1);
    for (int g = 0; g < 8; g++) {
      int swz = quad ^ (lcol & 3) ^ ((lcol >> 2) & 3);  // row = g*16+lcol
      bf16x8 vfr = *(const bf16x8*)(Vb + (size_t)(g * 16 + lcol) * 32 + swz * 8);
      for (int m = 0; m < 2; m++)
        o[m][g] = mfma16(pa[m], vfr, o[m][g]);
    }
    for (int m = 0; m < 2; m++)
      al[m] = mfma16(pa[m], ones, al[m]);
    __builtin_amdgcn_s_setprio(0);
  }

  for (int m = 0; m < 2; m++) {
    u16* op = ao + (size_t)(b * S_ + q0 + m * 16 + quad * 4) * D_ + h * DH_ + lcol;
    for (int r = 0; r < 4; r++) {
      float inv = 1.0f / al[m][r];
      for (int g = 0; g < 8; g++)
        op[(size_t)r * D_ + g * 16] = f2bf(o[m][g][r] * inv);
    }
  }
}

extern "C" void kernel_launch(void* const* d_in, const int* in_sizes, int n_in,
                              void* d_out, int out_size, void* d_ws, size_t ws_size,
                              hipStream_t stream)
{
  (void)in_sizes; (void)n_in; (void)out_size;
  const float* q  = (const float*)d_in[0];
  const float* k  = (const float*)d_in[1];
  const float* v  = (const float*)d_in[2];
  const float* Wq = (const float*)d_in[3];
  const float* bq = (const float*)d_in[4];
  const float* Wk = (const float*)d_in[5];
  const float* bk = (const float*)d_in[6];
  const float* Wv = (const float*)d_in[7];
  const float* bv = (const float*)d_in[8];
  const float* Wo = (const float*)d_in[9];
  const float* bo = (const float*)d_in[10];
  float* out = (float*)d_out;

  char* ws = (char*)d_ws;
  size_t off = 0;
  auto alloc = [&](size_t bytes) -> char* {
    char* p = ws + off; off += (bytes + 255) & ~(size_t)255; return p;
  };
  u16* xbf = (u16*)alloc((size_t)M_ * D_ * 2);    // k-cast, then q-cast, then ao
  u16* qh  = (u16*)alloc((size_t)M_ * D_ * 2);    // v-cast temp, then Q-proj out
  u16* kh  = (u16*)alloc((size_t)M_ * DH_ * 2);
  u16* vh  = (u16*)alloc((size_t)M_ * DH_ * 2);
  u16* vhT = (u16*)alloc((size_t)M_ * DH_ * 2);
  u16* WqT = (u16*)alloc((size_t)D_ * D_ * 2);
  u16* WkT = (u16*)alloc((size_t)DH_ * D_ * 2);
  u16* WvT = (u16*)alloc((size_t)DH_ * D_ * 2);
  u16* WoT = (u16*)alloc((size_t)D_ * D_ * 2);
  u16* ao  = xbf;   // xbf dead after Q-proj GEMM

  if (off > ws_size) return;  // diagnosable failure instead of OOB fault

  const int n4 = M_ * D_ / 4;

  transpose_bf<<<dim3(D_/32,  D_/32), dim3(32, 8), 0, stream>>>(Wq, WqT, D_, D_);
  transpose_bf<<<dim3(DH_/32, D_/32), dim3(32, 8), 0, stream>>>(Wk, WkT, D_, DH_);
  transpose_bf<<<dim3(DH_/32, D_/32), dim3(32, 8), 0, stream>>>(Wv, WvT, D_, DH_);
  transpose_bf<<<dim3(D_/32,  D_/32), dim3(32, 8), 0, stream>>>(Wo, WoT, D_, D_);

  // K + V cast (one dispatch): k->xbf, v->qh (qh free until Q-proj)
  cvt_bf16_2<<<dim3(n4 / 256, 2), dim3(256), 0, stream>>>(k, v, xbf, qh, n4);
  // K + V projection (one dispatch, 512 blocks)
  gemm_kv<<<dim3(M_/32, 1, 2), dim3(256), 0, stream>>>(
      xbf, qh, WkT, WvT, bk, bv, kh, vh);
  transpose_vh<<<dim3(DH_/32, S_/32, B_), dim3(32, 8), 0, stream>>>(vh, vhT);
  // Q projection
  cvt_bf16<<<dim3(n4 / 256), dim3(256), 0, stream>>>(q, xbf, n4);
  gemm_bt<0><<<dim3(D_/128,  M_/128), dim3(256), 0, stream>>>(xbf, WqT, bq, qh, M_, D_, D_);

  // Attention (writes ao == xbf, merged heads)
  mqa_attn<<<dim3(S_/128, H_, B_), dim3(256), 0, stream>>>(qh, kh, vhT, ao);

  // Output projection (fp32 out + bias)
  gemm_bt<1><<<dim3(D_/128, M_/128), dim3(256), 0, stream>>>(ao, WoT, bo, out, M_, D_, D_);
}

// Round 6
// 613.481 us; speedup vs baseline: 1.3229x; 1.1157x over previous
//
#include <hip/hip_runtime.h>
#include <stdint.h>

#define B_  4
#define S_  2048
#define D_  2048
#define H_  16
#define DH_ 128
#define M_  (B_*S_)

typedef unsigned short u16;
typedef __bf16 bf16x8 __attribute__((ext_vector_type(8)));
typedef float  f32x4  __attribute__((ext_vector_type(4)));
typedef u16    u16x4  __attribute__((ext_vector_type(4)));

__device__ __forceinline__ u16 f2bf(float f){
  unsigned x = __float_as_uint(f);
  x += 0x7fffu + ((x >> 16) & 1u);          // RNE
  return (u16)(x >> 16);
}

// v_cvt_pk_bf16_f32: D[15:0]=bf16(lo), D[31:16]=bf16(hi). No HIP builtin (m240).
__device__ __forceinline__ unsigned pkbf(float lo, float hi){
  unsigned r;
  asm("v_cvt_pk_bf16_f32 %0, %1, %2" : "=v"(r) : "v"(lo), "v"(hi));
  return r;
}

// Async global->LDS, 16B per lane. LDS dest = wave-uniform base + lane*16.
__device__ __forceinline__ void stage16(const void* g, void* lds_base){
  __builtin_amdgcn_global_load_lds(
      (const __attribute__((address_space(1))) void*)g,
      (__attribute__((address_space(3))) void*)lds_base, 16, 0, 0);
}

__device__ __forceinline__ f32x4 mfma16(bf16x8 a, bf16x8 b, f32x4 c){
  return __builtin_amdgcn_mfma_f32_16x16x32_bf16(a, b, c, 0, 0, 0);
}

// ---------------- fp32 -> bf16 cast (vectorized) ----------------
__global__ void cvt_bf16(const float* __restrict__ s, u16* __restrict__ d, int n4){
  int i = blockIdx.x * 256 + threadIdx.x;
  if (i >= n4) return;
  float4 f = ((const float4*)s)[i];
  u16x4 u = { f2bf(f.x), f2bf(f.y), f2bf(f.z), f2bf(f.w) };
  ((u16x4*)d)[i] = u;
}

// Fused dual cast: blockIdx.y selects (s0->d0) or (s1->d1).
__global__ void cvt_bf16_2(const float* __restrict__ s0, const float* __restrict__ s1,
                           u16* __restrict__ d0, u16* __restrict__ d1, int n4){
  const float* s = blockIdx.y ? s1 : s0;
  u16*        d = blockIdx.y ? d1 : d0;
  int i = blockIdx.x * 256 + threadIdx.x;
  if (i >= n4) return;
  float4 f = ((const float4*)s)[i];
  u16x4 u = { f2bf(f.x), f2bf(f.y), f2bf(f.z), f2bf(f.w) };
  ((u16x4*)d)[i] = u;
}

// ---------------- W [K][N] fp32 -> WT [N][K] bf16 ----------------
__global__ void transpose_bf(const float* __restrict__ W, u16* __restrict__ WT, int K, int N){
  __shared__ float tl[32][33];
  int n0 = blockIdx.x * 32, k0 = blockIdx.y * 32;
  int tx = threadIdx.x, ty = threadIdx.y;     // block (32,8)
  for (int r = 0; r < 4; r++)
    tl[ty + 8*r][tx] = W[(size_t)(k0 + ty + 8*r) * N + n0 + tx];
  __syncthreads();
  for (int r = 0; r < 4; r++)
    WT[(size_t)(n0 + ty + 8*r) * K + k0 + tx] = f2bf(tl[tx][ty + 8*r]);
}

// -------- vh [B*S][DH] bf16 -> vhT [B][DH][S] bf16 --------
__global__ void transpose_vh(const u16* __restrict__ vh, u16* __restrict__ vhT){
  __shared__ u16 tl[32][33];
  int b = blockIdx.z, d0 = blockIdx.x * 32, s0 = blockIdx.y * 32;
  int tx = threadIdx.x, ty = threadIdx.y;     // block (32,8)
  for (int r = 0; r < 4; r++)
    tl[ty + 8*r][tx] = vh[(size_t)(b * S_ + s0 + ty + 8*r) * DH_ + d0 + tx];
  __syncthreads();
  for (int r = 0; r < 4; r++)
    vhT[(size_t)(b * DH_ + d0 + ty + 8*r) * S_ + s0 + tx] = tl[tx][ty + 8*r];
}

// ============ 256x256 8-phase GEMM: C[M,2048] = A[M,2048] @ BT[2048,2048]^T ============
// Port of the m201 8-phase template (T2 swizzle + T3/T4 counted vmcnt + T5 setprio).
// 512 threads (8 waves), BK=64, LDS 128KB (2 dbuf x {A,B} x 256x64 bf16), 1 block/CU.
// Quadrant gray-order per K-tile: P0=(A0,B0) P1=(A0,B1) P2=(A1,B1) P3=(A1,B0).
// Per-wave per phase: 2 M-frags x 4 N-frags x 2 kk = 16 MFMA, 12 ds_read_b128.
// Stage plan per tile T (1 half-tile per phase, 2 gload_lds/thread):
//   p0:(T+1):B0  p1:(T+1):A1  -> buf[(T+1)&1] (fully dead: held T-1)
//   p2:(T+2):A0  p3:(T+2):B1  -> buf[T&1]     (A0 dead after P1, B1 dead after P2)
// Wait: vmcnt(4) at end of p3 BEFORE closing barrier => tile T+1 fully landed,
// [T+2:A0, T+2:B1] (4 loads) stay in flight. vmcnt(0) for the last two tiles.
// LDS chunk swizzle: stored chunk = c ^ (row&7); gload_lds keeps LDS linear and
// pre-swizzles the GLOBAL chunk (m173 pattern, 0 bank conflicts in attn probes).
template<int OUTF32>
__global__ __launch_bounds__(512, 1) void gemm256(const u16* __restrict__ A,
    const u16* __restrict__ BT, const float* __restrict__ bias, void* __restrict__ Cv)
{
  __shared__ alignas(16) u16 AB[2][2][2 * 128 * 64];   // [buf][A/B][half*8192 + row*64 + col]
  const int t = threadIdx.x, lane = t & 63, wave = t >> 6;
  const int quad = lane >> 4, lcol = lane & 15;
  const int wr = wave >> 1, wc = wave & 1;     // 4 row-groups x 2 col-groups per quadrant
  const int m0 = blockIdx.y * 256, n0 = blockIdx.x * 256;
  const int NT = 2048 / 64;

  // Stage one half-tile (128 rows x 64 cols bf16 = 16KB): 2 gload_lds per thread.
  auto stageH = [&](const u16* g, int grow0, int kcol0, u16* lb){
    #pragma unroll
    for (int i = 0; i < 2; i++){
      int l = (i*8 + wave)*64 + lane;          // linear 16B-chunk id 0..1023
      int row = l >> 3, st = l & 7;
      int c = st ^ (row & 7);                  // pre-swizzled global chunk
      stage16(g + (size_t)(grow0 + row)*2048 + kcol0 + c*8, lb + (size_t)(i*8 + wave)*512);
    }
  };

  f32x4 acc[4][2][4] = {};                     // [quadrant][m][n] = 128 VGPR

  // Prologue: T0 all 4 halves + T1:{A0,B1}; wait so T0 landed, 2 halves in flight.
  stageH(A,  m0,       0,  &AB[0][0][0]);
  stageH(BT, n0,       0,  &AB[0][1][0]);
  stageH(BT, n0 + 128, 0,  &AB[0][1][8192]);
  stageH(A,  m0 + 128, 0,  &AB[0][0][8192]);
  stageH(A,  m0,       64, &AB[1][0][0]);
  stageH(BT, n0 + 128, 64, &AB[1][1][8192]);
  asm volatile("s_waitcnt vmcnt(4)" ::: "memory");
  __builtin_amdgcn_s_barrier();

  for (int T = 0; T < NT; ++T) {
    const int bi = T & 1;
    const u16* Ab = &AB[bi][0][0];
    const u16* Bb = &AB[bi][1][0];
    #pragma unroll
    for (int q = 0; q < 4; ++q) {
      const int ah = q >> 1, bh = (q >> 1) ^ (q & 1);
      // ds-reads for this quadrant (12 x ds_read_b128)
      bf16x8 af[2][2], bv[4][2];
      #pragma unroll
      for (int m = 0; m < 2; m++) {
        const u16* ap = Ab + (size_t)(ah*128 + wr*32 + m*16 + lcol) * 64;
        #pragma unroll
        for (int kk = 0; kk < 2; kk++)
          af[m][kk] = *(const bf16x8*)(ap + (((kk*4 + quad) ^ (lcol & 7)) * 8));
      }
      #pragma unroll
      for (int n = 0; n < 4; n++) {
        const u16* bp = Bb + (size_t)(bh*128 + wc*64 + n*16 + lcol) * 64;
        #pragma unroll
        for (int kk = 0; kk < 2; kk++)
          bv[n][kk] = *(const bf16x8*)(bp + (((kk*4 + quad) ^ (lcol & 7)) * 8));
      }
      // stage issue (1 half-tile per phase)
      if      (q == 0 && T + 1 < NT) stageH(BT, n0,       (T+1)*64, &AB[(T+1)&1][1][0]);
      else if (q == 1 && T + 1 < NT) stageH(A,  m0 + 128, (T+1)*64, &AB[(T+1)&1][0][8192]);
      else if (q == 2 && T + 2 < NT) stageH(A,  m0,       (T+2)*64, &AB[bi][0][0]);
      else if (q == 3 && T + 2 < NT) stageH(BT, n0 + 128, (T+2)*64, &AB[bi][1][8192]);

      __builtin_amdgcn_s_barrier();
      asm volatile("s_waitcnt lgkmcnt(0)" ::: "memory");
      __builtin_amdgcn_sched_barrier(0);
      __builtin_amdgcn_s_setprio(1);
      #pragma unroll
      for (int m = 0; m < 2; m++)
        #pragma unroll
        for (int n = 0; n < 4; n++)
          #pragma unroll
          for (int kk = 0; kk < 2; kk++)
            acc[q][m][n] = mfma16(af[m][kk], bv[n][kk], acc[q][m][n]);
      __builtin_amdgcn_s_setprio(0);
      if (q == 3) {
        if (T < NT - 2) { asm volatile("s_waitcnt vmcnt(4)" ::: "memory"); }
        else            { asm volatile("s_waitcnt vmcnt(0)" ::: "memory"); }
      }
      __builtin_amdgcn_s_barrier();
    }
  }

  // Epilogue
  #pragma unroll
  for (int q = 0; q < 4; ++q) {
    const int ah = q >> 1, bh = (q >> 1) ^ (q & 1);
    #pragma unroll
    for (int n = 0; n < 4; n++) {
      int col = n0 + bh*128 + wc*64 + n*16 + lcol;
      float bj = bias[col];
      #pragma unroll
      for (int m = 0; m < 2; m++) {
        int rowb = m0 + ah*128 + wr*32 + m*16 + quad*4;
        #pragma unroll
        for (int r = 0; r < 4; r++) {
          float vv = acc[q][m][n][r] + bj;
          if (OUTF32) ((float*)Cv)[(size_t)(rowb + r) * 2048 + col] = vv;
          else        ((u16*)Cv)  [(size_t)(rowb + r) * 2048 + col] = f2bf(vv);
        }
      }
    }
  }
}

// -------- Fused K/V projection: C[M,128] = A[M,2048] @ BT[128,2048]^T + bias --------
__global__ __launch_bounds__(256) void gemm_kv(
    const u16* __restrict__ A0, const u16* __restrict__ A1,
    const u16* __restrict__ BT0, const u16* __restrict__ BT1,
    const float* __restrict__ b0, const float* __restrict__ b1,
    u16* __restrict__ C0, u16* __restrict__ C1)
{
  const int sel = blockIdx.z;
  const u16* A  = sel ? A1 : A0;
  const u16* BT = sel ? BT1 : BT0;
  const float* bias = sel ? b1 : b0;
  u16* C = sel ? C1 : C0;

  __shared__ alignas(16) u16 Al[32 * 32];    // 2 KB
  __shared__ alignas(16) u16 Bl[128 * 32];   // 8 KB
  const int t = threadIdx.x, lane = t & 63, wave = t >> 6;
  const int quad = lane >> 4, lcol = lane & 15;
  const int m0 = blockIdx.x * 32;

  f32x4 acc[2][2] = {};
  for (int k0 = 0; k0 < D_; k0 += 32) {
    if (t < 128) {
      int row = t >> 2, kc = t & 3;
      stage16(A + (size_t)(m0 + row) * D_ + k0 + kc * 8, Al + (wave * 64) * 8);
    } else {
      int bc = t - 128, row = bc >> 2, kc = bc & 3;
      stage16(BT + (size_t)row * D_ + k0 + kc * 8, Bl + ((wave - 2) * 64) * 8);
    }
    {
      int bc = t + 128, row = bc >> 2, kc = bc & 3;
      stage16(BT + (size_t)row * D_ + k0 + kc * 8, Bl + (128 + wave * 64) * 8);
    }
    if (t < 128) {
      int bc = t + 384, row = bc >> 2, kc = bc & 3;
      stage16(BT + (size_t)row * D_ + k0 + kc * 8, Bl + (384 + wave * 64) * 8);
    }
    __syncthreads();
    bf16x8 af[2], bfr[2];
    for (int i = 0; i < 2; i++)
      af[i]  = *(const bf16x8*)(Al + (i*16 + lcol) * 32 + quad * 8);
    for (int j = 0; j < 2; j++)
      bfr[j] = *(const bf16x8*)(Bl + (wave*32 + j*16 + lcol) * 32 + quad * 8);
    for (int i = 0; i < 2; i++)
      for (int j = 0; j < 2; j++)
        acc[i][j] = mfma16(af[i], bfr[j], acc[i][j]);
    __syncthreads();
  }
  for (int j = 0; j < 2; j++) {
    int n = wave * 32 + j * 16 + lcol;
    float bj = bias[n];
    for (int i = 0; i < 2; i++) {
      int mbase = m0 + i * 16 + quad * 4;
      for (int r = 0; r < 4; r++)
        C[(size_t)(mbase + r) * DH_ + n] = f2bf(acc[i][j][r] + bj);
    }
  }
}

// ---------------- Flash attention v6 (unchanged: 197us, 0-spill, 3 waves/SIMD) -----
__global__ __launch_bounds__(256, 3) void mqa_attn(const u16* __restrict__ qh,
    const u16* __restrict__ kh, const u16* __restrict__ vhT, u16* __restrict__ ao)
{
  __shared__ alignas(16) u16 Kl[2][32 * 128]; // [kv][dh], 16B-chunk swizzle st^(row&15)
  __shared__ alignas(16) u16 Vl[2][128 * 32]; // [dh][kv], swizzle st^(row&3)^((row>>2)&3)
  const int t = threadIdx.x, lane = t & 63, wave = t >> 6;
  const int quad = lane >> 4, lcol = lane & 15;
  const int b = blockIdx.z, h = blockIdx.y;
  const int q0 = blockIdx.x * 128 + wave * 32;         // 32 rows per wave
  const float sc2 = 0.12751743f;             // (1/sqrt(128)) * log2(e)

  bf16x8 qf[2][4];
  for (int m = 0; m < 2; m++) {
    const u16* qp = qh + (size_t)(b * S_ + q0 + m * 16 + lcol) * D_ + h * DH_ + quad * 8;
    for (int kk = 0; kk < 4; kk++) qf[m][kk] = *(const bf16x8*)(qp + kk * 32);
  }
  union { u16 u[8]; bf16x8 v; } one_u;
  for (int i = 0; i < 8; i++) one_u.u[i] = 0x3F80;
  const bf16x8 ones = one_u.v;

  f32x4 o[2][8] = {};
  f32x4 al[2] = {};
  const u16* kb = kh  + (size_t)b * S_ * DH_;
  const u16* vb = vhT + (size_t)b * DH_ * S_;

  auto stageKV = [&](int tt, int bi) {
    int kv0 = tt * 32;
    for (int p = 0; p < 2; p++) {
      int c = p * 256 + wave * 64 + lane;
      int row = c >> 4, st = c & 15;
      int kc = st ^ (row & 15);
      stage16(kb + (size_t)(kv0 + row) * DH_ + kc * 8, &Kl[bi][(p*256 + wave*64) * 8]);
    }
    for (int p = 0; p < 2; p++) {
      int c = p * 256 + wave * 64 + lane;
      int row = c >> 2, st = c & 3;
      int kc = st ^ (row & 3) ^ ((row >> 2) & 3);
      stage16(vb + (size_t)row * S_ + kv0 + kc * 8, &Vl[bi][(p*256 + wave*64) * 8]);
    }
  };

  stageKV(0, 0);
  for (int tt = 0; tt < S_ / 32; tt++) {
    const int bi = tt & 1;
    __syncthreads();                       // drains staging of tile tt; fences buf bi^1
    if (tt < S_ / 32 - 1) stageKV(tt + 1, bi ^ 1);   // in flight during compute

    const u16* Kb = &Kl[bi][0];
    const u16* Vb = &Vl[bi][0];

    unsigned cc[2][4];
    for (int kvf = 0; kvf < 2; kvf++) {
      f32x4 s[2] = {};
      const u16* kp = Kb + (size_t)(kvf * 16 + lcol) * 128;   // row&15 == lcol
      __builtin_amdgcn_s_setprio(1);
      for (int kk = 0; kk < 4; kk++) {
        int swz = (kk * 4 + quad) ^ lcol;
        bf16x8 kfr = *(const bf16x8*)(kp + swz * 8);
        for (int m = 0; m < 2; m++)
          s[m] = mfma16(kfr, qf[m][kk], s[m]);
      }
      __builtin_amdgcn_s_setprio(0);
      for (int m = 0; m < 2; m++) {
        float e0 = exp2f(s[m][0] * sc2), e1 = exp2f(s[m][1] * sc2);
        float e2 = exp2f(s[m][2] * sc2), e3 = exp2f(s[m][3] * sc2);
        cc[m][kvf * 2 + 0] = pkbf(e0, e1);
        cc[m][kvf * 2 + 1] = pkbf(e2, e3);
      }
    }
    bf16x8 pa[2];
    for (int m = 0; m < 2; m++) {
      asm("v_permlane32_swap_b32 %0, %1" : "+v"(cc[m][0]), "+v"(cc[m][2]));
      asm("v_permlane16_swap_b32 %0, %1" : "+v"(cc[m][0]), "+v"(cc[m][2]));
      asm("v_permlane32_swap_b32 %0, %1" : "+v"(cc[m][1]), "+v"(cc[m][3]));
      asm("v_permlane16_swap_b32 %0, %1" : "+v"(cc[m][1]), "+v"(cc[m][3]));
      union { unsigned u[4]; bf16x8 v; } pu;
      pu.u[0] = cc[m][0];
      pu.u[1] = cc[m][1];
      pu.u[2] = cc[m][2];
      pu.u[3] = cc[m][3];
      pa[m] = pu.v;
    }

    __builtin_amdgcn_s_setprio(1);
    for (int g = 0; g < 8; g++) {
      int swz = quad ^ (lcol & 3) ^ ((lcol >> 2) & 3);  // row = g*16+lcol
      bf16x8 vfr = *(const bf16x8*)(Vb + (size_t)(g * 16 + lcol) * 32 + swz * 8);
      for (int m = 0; m < 2; m++)
        o[m][g] = mfma16(pa[m], vfr, o[m][g]);
    }
    for (int m = 0; m < 2; m++)
      al[m] = mfma16(pa[m], ones, al[m]);
    __builtin_amdgcn_s_setprio(0);
  }

  for (int m = 0; m < 2; m++) {
    u16* op = ao + (size_t)(b * S_ + q0 + m * 16 + quad * 4) * D_ + h * DH_ + lcol;
    for (int r = 0; r < 4; r++) {
      float inv = 1.0f / al[m][r];
      for (int g = 0; g < 8; g++)
        op[(size_t)r * D_ + g * 16] = f2bf(o[m][g][r] * inv);
    }
  }
}

extern "C" void kernel_launch(void* const* d_in, const int* in_sizes, int n_in,
                              void* d_out, int out_size, void* d_ws, size_t ws_size,
                              hipStream_t stream)
{
  (void)in_sizes; (void)n_in; (void)out_size;
  const float* q  = (const float*)d_in[0];
  const float* k  = (const float*)d_in[1];
  const float* v  = (const float*)d_in[2];
  const float* Wq = (const float*)d_in[3];
  const float* bq = (const float*)d_in[4];
  const float* Wk = (const float*)d_in[5];
  const float* bk = (const float*)d_in[6];
  const float* Wv = (const float*)d_in[7];
  const float* bv = (const float*)d_in[8];
  const float* Wo = (const float*)d_in[9];
  const float* bo = (const float*)d_in[10];
  float* out = (float*)d_out;

  char* ws = (char*)d_ws;
  size_t off = 0;
  auto alloc = [&](size_t bytes) -> char* {
    char* p = ws + off; off += (bytes + 255) & ~(size_t)255; return p;
  };
  u16* xbf = (u16*)alloc((size_t)M_ * D_ * 2);    // k-cast, then q-cast, then ao
  u16* qh  = (u16*)alloc((size_t)M_ * D_ * 2);    // v-cast temp, then Q-proj out
  u16* kh  = (u16*)alloc((size_t)M_ * DH_ * 2);
  u16* vh  = (u16*)alloc((size_t)M_ * DH_ * 2);
  u16* vhT = (u16*)alloc((size_t)M_ * DH_ * 2);
  u16* WqT = (u16*)alloc((size_t)D_ * D_ * 2);
  u16* WkT = (u16*)alloc((size_t)DH_ * D_ * 2);
  u16* WvT = (u16*)alloc((size_t)DH_ * D_ * 2);
  u16* WoT = (u16*)alloc((size_t)D_ * D_ * 2);
  u16* ao  = xbf;   // xbf dead after Q-proj GEMM

  if (off > ws_size) return;  // diagnosable failure instead of OOB fault

  const int n4 = M_ * D_ / 4;

  transpose_bf<<<dim3(D_/32,  D_/32), dim3(32, 8), 0, stream>>>(Wq, WqT, D_, D_);
  transpose_bf<<<dim3(DH_/32, D_/32), dim3(32, 8), 0, stream>>>(Wk, WkT, D_, DH_);
  transpose_bf<<<dim3(DH_/32, D_/32), dim3(32, 8), 0, stream>>>(Wv, WvT, D_, DH_);
  transpose_bf<<<dim3(D_/32,  D_/32), dim3(32, 8), 0, stream>>>(Wo, WoT, D_, D_);

  // K + V cast (one dispatch): k->xbf, v->qh (qh free until Q-proj)
  cvt_bf16_2<<<dim3(n4 / 256, 2), dim3(256), 0, stream>>>(k, v, xbf, qh, n4);
  // K + V projection (one dispatch, 512 blocks)
  gemm_kv<<<dim3(M_/32, 1, 2), dim3(256), 0, stream>>>(
      xbf, qh, WkT, WvT, bk, bv, kh, vh);
  transpose_vh<<<dim3(DH_/32, S_/32, B_), dim3(32, 8), 0, stream>>>(vh, vhT);
  // Q projection (8-phase 256^2 GEMM, 256 blocks = 1/CU)
  cvt_bf16<<<dim3(n4 / 256), dim3(256), 0, stream>>>(q, xbf, n4);
  gemm256<0><<<dim3(D_/256, M_/256), dim3(512), 0, stream>>>(xbf, WqT, bq, qh);

  // Attention (writes ao == xbf, merged heads)
  mqa_attn<<<dim3(S_/128, H_, B_), dim3(256), 0, stream>>>(qh, kh, vhT, ao);

  // Output projection (fp32 out + bias)
  gemm256<1><<<dim3(D_/256, M_/256), dim3(512), 0, stream>>>(ao, WoT, bo, out);
}

// Round 7
// 600.632 us; speedup vs baseline: 1.3512x; 1.0214x over previous
//
#include <hip/hip_runtime.h>
#include <stdint.h>

#define B_  4
#define S_  2048
#define D_  2048
#define H_  16
#define DH_ 128
#define M_  (B_*S_)

typedef unsigned short u16;
typedef __bf16 bf16x8 __attribute__((ext_vector_type(8)));
typedef float  f32x4  __attribute__((ext_vector_type(4)));
typedef u16    u16x4  __attribute__((ext_vector_type(4)));

__device__ __forceinline__ u16 f2bf(float f){
  unsigned x = __float_as_uint(f);
  x += 0x7fffu + ((x >> 16) & 1u);          // RNE
  return (u16)(x >> 16);
}

// v_cvt_pk_bf16_f32: D[15:0]=bf16(lo), D[31:16]=bf16(hi). No HIP builtin (m240).
__device__ __forceinline__ unsigned pkbf(float lo, float hi){
  unsigned r;
  asm("v_cvt_pk_bf16_f32 %0, %1, %2" : "=v"(r) : "v"(lo), "v"(hi));
  return r;
}

// Async global->LDS, 16B per lane. LDS dest = wave-uniform base + lane*16.
__device__ __forceinline__ void stage16(const void* g, void* lds_base){
  __builtin_amdgcn_global_load_lds(
      (const __attribute__((address_space(1))) void*)g,
      (__attribute__((address_space(3))) void*)lds_base, 16, 0, 0);
}

__device__ __forceinline__ f32x4 mfma16(bf16x8 a, bf16x8 b, f32x4 c){
  return __builtin_amdgcn_mfma_f32_16x16x32_bf16(a, b, c, 0, 0, 0);
}

// ---------------- fp32 -> bf16 cast (vectorized) ----------------
__global__ void cvt_bf16(const float* __restrict__ s, u16* __restrict__ d, int n4){
  int i = blockIdx.x * 256 + threadIdx.x;
  if (i >= n4) return;
  float4 f = ((const float4*)s)[i];
  u16x4 u = { f2bf(f.x), f2bf(f.y), f2bf(f.z), f2bf(f.w) };
  ((u16x4*)d)[i] = u;
}

// Fused dual cast: blockIdx.y selects (s0->d0) or (s1->d1).
__global__ void cvt_bf16_2(const float* __restrict__ s0, const float* __restrict__ s1,
                           u16* __restrict__ d0, u16* __restrict__ d1, int n4){
  const float* s = blockIdx.y ? s1 : s0;
  u16*        d = blockIdx.y ? d1 : d0;
  int i = blockIdx.x * 256 + threadIdx.x;
  if (i >= n4) return;
  float4 f = ((const float4*)s)[i];
  u16x4 u = { f2bf(f.x), f2bf(f.y), f2bf(f.z), f2bf(f.w) };
  ((u16x4*)d)[i] = u;
}

// ---------------- W [K][N] fp32 -> WT [N][K] bf16 ----------------
__global__ void transpose_bf(const float* __restrict__ W, u16* __restrict__ WT, int K, int N){
  __shared__ float tl[32][33];
  int n0 = blockIdx.x * 32, k0 = blockIdx.y * 32;
  int tx = threadIdx.x, ty = threadIdx.y;     // block (32,8)
  for (int r = 0; r < 4; r++)
    tl[ty + 8*r][tx] = W[(size_t)(k0 + ty + 8*r) * N + n0 + tx];
  __syncthreads();
  for (int r = 0; r < 4; r++)
    WT[(size_t)(n0 + ty + 8*r) * K + k0 + tx] = f2bf(tl[tx][ty + 8*r]);
}

// -------- vh [B*S][DH] bf16 -> vhT [B][DH][S] bf16 --------
__global__ void transpose_vh(const u16* __restrict__ vh, u16* __restrict__ vhT){
  __shared__ u16 tl[32][33];
  int b = blockIdx.z, d0 = blockIdx.x * 32, s0 = blockIdx.y * 32;
  int tx = threadIdx.x, ty = threadIdx.y;     // block (32,8)
  for (int r = 0; r < 4; r++)
    tl[ty + 8*r][tx] = vh[(size_t)(b * S_ + s0 + ty + 8*r) * DH_ + d0 + tx];
  __syncthreads();
  for (int r = 0; r < 4; r++)
    vhT[(size_t)(b * DH_ + d0 + ty + 8*r) * S_ + s0 + tx] = tl[tx][ty + 8*r];
}

// ============ 256x256 8-phase GEMM: C[M,2048] = A[M,2048] @ BT[2048,2048]^T ============
// r6 analysis: this kernel was FETCH-bound, not schedule-bound. Each block reads
// A-panel 1MB + B-panel 1MB; consecutive blocks sharing a panel round-robin
// across the 8 per-XCD L2s -> zero cross-block reuse -> 512 MB/dispatch HBM.
// r7 fix (T1, m192): bijective XCD swizzle, swz=(bid&7)*32+(bid>>3) (256%8==0).
// Each XCD owns an 8n x 4m chunk; co-resident K-synchronized blocks share a
// 384 KB per-K-slab working set in L2 -> ~110 MB total fetch.
// Schedule: m201 8-phase port (T2 swizzle + T3/T4 counted vmcnt + T5 setprio).
// 512 threads (8 waves), BK=64, LDS 128KB, 1 block/CU, quadrant gray-order,
// 1 half-tile staged per phase, vmcnt(4) at q3 (2 half-tiles in flight).
template<int OUTF32>
__global__ __launch_bounds__(512, 1) void gemm256(const u16* __restrict__ A,
    const u16* __restrict__ BT, const float* __restrict__ bias, void* __restrict__ Cv)
{
  __shared__ alignas(16) u16 AB[2][2][2 * 128 * 64];   // [buf][A/B][half*8192 + row*64 + col]
  const int t = threadIdx.x, lane = t & 63, wave = t >> 6;
  const int quad = lane >> 4, lcol = lane & 15;
  const int wr = wave >> 1, wc = wave & 1;     // 4 row-groups x 2 col-groups per quadrant
  // XCD-aware bijective swizzle: 256 blocks, 8 XCDs, 32 blocks/XCD contiguous.
  const int bid = blockIdx.x;
  const int swz = (bid & 7) * 32 + (bid >> 3);
  const int n0 = (swz & 7) * 256, m0 = (swz >> 3) * 256;
  const int NT = 2048 / 64;

  // Stage one half-tile (128 rows x 64 cols bf16 = 16KB): 2 gload_lds per thread.
  auto stageH = [&](const u16* g, int grow0, int kcol0, u16* lb){
    #pragma unroll
    for (int i = 0; i < 2; i++){
      int l = (i*8 + wave)*64 + lane;          // linear 16B-chunk id 0..1023
      int row = l >> 3, st = l & 7;
      int c = st ^ (row & 7);                  // pre-swizzled global chunk
      stage16(g + (size_t)(grow0 + row)*2048 + kcol0 + c*8, lb + (size_t)(i*8 + wave)*512);
    }
  };

  f32x4 acc[4][2][4] = {};                     // [quadrant][m][n] = 128 VGPR

  // Prologue: T0 all 4 halves + T1:{A0,B1}; wait so T0 landed, 2 halves in flight.
  stageH(A,  m0,       0,  &AB[0][0][0]);
  stageH(BT, n0,       0,  &AB[0][1][0]);
  stageH(BT, n0 + 128, 0,  &AB[0][1][8192]);
  stageH(A,  m0 + 128, 0,  &AB[0][0][8192]);
  stageH(A,  m0,       64, &AB[1][0][0]);
  stageH(BT, n0 + 128, 64, &AB[1][1][8192]);
  asm volatile("s_waitcnt vmcnt(4)" ::: "memory");
  __builtin_amdgcn_s_barrier();

  for (int T = 0; T < NT; ++T) {
    const int bi = T & 1;
    const u16* Ab = &AB[bi][0][0];
    const u16* Bb = &AB[bi][1][0];
    #pragma unroll
    for (int q = 0; q < 4; ++q) {
      const int ah = q >> 1, bh = (q >> 1) ^ (q & 1);
      // ds-reads for this quadrant (12 x ds_read_b128)
      bf16x8 af[2][2], bv[4][2];
      #pragma unroll
      for (int m = 0; m < 2; m++) {
        const u16* ap = Ab + (size_t)(ah*128 + wr*32 + m*16 + lcol) * 64;
        #pragma unroll
        for (int kk = 0; kk < 2; kk++)
          af[m][kk] = *(const bf16x8*)(ap + (((kk*4 + quad) ^ (lcol & 7)) * 8));
      }
      #pragma unroll
      for (int n = 0; n < 4; n++) {
        const u16* bp = Bb + (size_t)(bh*128 + wc*64 + n*16 + lcol) * 64;
        #pragma unroll
        for (int kk = 0; kk < 2; kk++)
          bv[n][kk] = *(const bf16x8*)(bp + (((kk*4 + quad) ^ (lcol & 7)) * 8));
      }
      // stage issue (1 half-tile per phase)
      if      (q == 0 && T + 1 < NT) stageH(BT, n0,       (T+1)*64, &AB[(T+1)&1][1][0]);
      else if (q == 1 && T + 1 < NT) stageH(A,  m0 + 128, (T+1)*64, &AB[(T+1)&1][0][8192]);
      else if (q == 2 && T + 2 < NT) stageH(A,  m0,       (T+2)*64, &AB[bi][0][0]);
      else if (q == 3 && T + 2 < NT) stageH(BT, n0 + 128, (T+2)*64, &AB[bi][1][8192]);

      __builtin_amdgcn_s_barrier();
      asm volatile("s_waitcnt lgkmcnt(0)" ::: "memory");
      __builtin_amdgcn_sched_barrier(0);
      __builtin_amdgcn_s_setprio(1);
      #pragma unroll
      for (int m = 0; m < 2; m++)
        #pragma unroll
        for (int n = 0; n < 4; n++)
          #pragma unroll
          for (int kk = 0; kk < 2; kk++)
            acc[q][m][n] = mfma16(af[m][kk], bv[n][kk], acc[q][m][n]);
      __builtin_amdgcn_s_setprio(0);
      if (q == 3) {
        if (T < NT - 2) { asm volatile("s_waitcnt vmcnt(4)" ::: "memory"); }
        else            { asm volatile("s_waitcnt vmcnt(0)" ::: "memory"); }
      }
      __builtin_amdgcn_s_barrier();
    }
  }

  // Epilogue
  #pragma unroll
  for (int q = 0; q < 4; ++q) {
    const int ah = q >> 1, bh = (q >> 1) ^ (q & 1);
    #pragma unroll
    for (int n = 0; n < 4; n++) {
      int col = n0 + bh*128 + wc*64 + n*16 + lcol;
      float bj = bias[col];
      #pragma unroll
      for (int m = 0; m < 2; m++) {
        int rowb = m0 + ah*128 + wr*32 + m*16 + quad*4;
        #pragma unroll
        for (int r = 0; r < 4; r++) {
          float vv = acc[q][m][n][r] + bj;
          if (OUTF32) ((float*)Cv)[(size_t)(rowb + r) * 2048 + col] = vv;
          else        ((u16*)Cv)  [(size_t)(rowb + r) * 2048 + col] = f2bf(vv);
        }
      }
    }
  }
}

// -------- Fused K/V projection: C[M,128] = A[M,2048] @ BT[128,2048]^T + bias --------
__global__ __launch_bounds__(256) void gemm_kv(
    const u16* __restrict__ A0, const u16* __restrict__ A1,
    const u16* __restrict__ BT0, const u16* __restrict__ BT1,
    const float* __restrict__ b0, const float* __restrict__ b1,
    u16* __restrict__ C0, u16* __restrict__ C1)
{
  const int sel = blockIdx.z;
  const u16* A  = sel ? A1 : A0;
  const u16* BT = sel ? BT1 : BT0;
  const float* bias = sel ? b1 : b0;
  u16* C = sel ? C1 : C0;

  __shared__ alignas(16) u16 Al[32 * 32];    // 2 KB
  __shared__ alignas(16) u16 Bl[128 * 32];   // 8 KB
  const int t = threadIdx.x, lane = t & 63, wave = t >> 6;
  const int quad = lane >> 4, lcol = lane & 15;
  const int m0 = blockIdx.x * 32;

  f32x4 acc[2][2] = {};
  for (int k0 = 0; k0 < D_; k0 += 32) {
    if (t < 128) {
      int row = t >> 2, kc = t & 3;
      stage16(A + (size_t)(m0 + row) * D_ + k0 + kc * 8, Al + (wave * 64) * 8);
    } else {
      int bc = t - 128, row = bc >> 2, kc = bc & 3;
      stage16(BT + (size_t)row * D_ + k0 + kc * 8, Bl + ((wave - 2) * 64) * 8);
    }
    {
      int bc = t + 128, row = bc >> 2, kc = bc & 3;
      stage16(BT + (size_t)row * D_ + k0 + kc * 8, Bl + (128 + wave * 64) * 8);
    }
    if (t < 128) {
      int bc = t + 384, row = bc >> 2, kc = bc & 3;
      stage16(BT + (size_t)row * D_ + k0 + kc * 8, Bl + (384 + wave * 64) * 8);
    }
    __syncthreads();
    bf16x8 af[2], bfr[2];
    for (int i = 0; i < 2; i++)
      af[i]  = *(const bf16x8*)(Al + (i*16 + lcol) * 32 + quad * 8);
    for (int j = 0; j < 2; j++)
      bfr[j] = *(const bf16x8*)(Bl + (wave*32 + j*16 + lcol) * 32 + quad * 8);
    for (int i = 0; i < 2; i++)
      for (int j = 0; j < 2; j++)
        acc[i][j] = mfma16(af[i], bfr[j], acc[i][j]);
    __syncthreads();
  }
  for (int j = 0; j < 2; j++) {
    int n = wave * 32 + j * 16 + lcol;
    float bj = bias[n];
    for (int i = 0; i < 2; i++) {
      int mbase = m0 + i * 16 + quad * 4;
      for (int r = 0; r < 4; r++)
        C[(size_t)(mbase + r) * DH_ + n] = f2bf(acc[i][j][r] + bj);
    }
  }
}

// ---------------- Flash attention v6 (unchanged: ~199us, 0-spill, 3 waves/SIMD) -----
__global__ __launch_bounds__(256, 3) void mqa_attn(const u16* __restrict__ qh,
    const u16* __restrict__ kh, const u16* __restrict__ vhT, u16* __restrict__ ao)
{
  __shared__ alignas(16) u16 Kl[2][32 * 128]; // [kv][dh], 16B-chunk swizzle st^(row&15)
  __shared__ alignas(16) u16 Vl[2][128 * 32]; // [dh][kv], swizzle st^(row&3)^((row>>2)&3)
  const int t = threadIdx.x, lane = t & 63, wave = t >> 6;
  const int quad = lane >> 4, lcol = lane & 15;
  const int b = blockIdx.z, h = blockIdx.y;
  const int q0 = blockIdx.x * 128 + wave * 32;         // 32 rows per wave
  const float sc2 = 0.12751743f;             // (1/sqrt(128)) * log2(e)

  bf16x8 qf[2][4];
  for (int m = 0; m < 2; m++) {
    const u16* qp = qh + (size_t)(b * S_ + q0 + m * 16 + lcol) * D_ + h * DH_ + quad * 8;
    for (int kk = 0; kk < 4; kk++) qf[m][kk] = *(const bf16x8*)(qp + kk * 32);
  }
  union { u16 u[8]; bf16x8 v; } one_u;
  for (int i = 0; i < 8; i++) one_u.u[i] = 0x3F80;
  const bf16x8 ones = one_u.v;

  f32x4 o[2][8] = {};
  f32x4 al[2] = {};
  const u16* kb = kh  + (size_t)b * S_ * DH_;
  const u16* vb = vhT + (size_t)b * DH_ * S_;

  auto stageKV = [&](int tt, int bi) {
    int kv0 = tt * 32;
    for (int p = 0; p < 2; p++) {
      int c = p * 256 + wave * 64 + lane;
      int row = c >> 4, st = c & 15;
      int kc = st ^ (row & 15);
      stage16(kb + (size_t)(kv0 + row) * DH_ + kc * 8, &Kl[bi][(p*256 + wave*64) * 8]);
    }
    for (int p = 0; p < 2; p++) {
      int c = p * 256 + wave * 64 + lane;
      int row = c >> 2, st = c & 3;
      int kc = st ^ (row & 3) ^ ((row >> 2) & 3);
      stage16(vb + (size_t)row * S_ + kv0 + kc * 8, &Vl[bi][(p*256 + wave*64) * 8]);
    }
  };

  stageKV(0, 0);
  for (int tt = 0; tt < S_ / 32; tt++) {
    const int bi = tt & 1;
    __syncthreads();                       // drains staging of tile tt; fences buf bi^1
    if (tt < S_ / 32 - 1) stageKV(tt + 1, bi ^ 1);   // in flight during compute

    const u16* Kb = &Kl[bi][0];
    const u16* Vb = &Vl[bi][0];

    unsigned cc[2][4];
    for (int kvf = 0; kvf < 2; kvf++) {
      f32x4 s[2] = {};
      const u16* kp = Kb + (size_t)(kvf * 16 + lcol) * 128;   // row&15 == lcol
      __builtin_amdgcn_s_setprio(1);
      for (int kk = 0; kk < 4; kk++) {
        int swz = (kk * 4 + quad) ^ lcol;
        bf16x8 kfr = *(const bf16x8*)(kp + swz * 8);
        for (int m = 0; m < 2; m++)
          s[m] = mfma16(kfr, qf[m][kk], s[m]);
      }
      __builtin_amdgcn_s_setprio(0);
      for (int m = 0; m < 2; m++) {
        float e0 = exp2f(s[m][0] * sc2), e1 = exp2f(s[m][1] * sc2);
        float e2 = exp2f(s[m][2] * sc2), e3 = exp2f(s[m][3] * sc2);
        cc[m][kvf * 2 + 0] = pkbf(e0, e1);
        cc[m][kvf * 2 + 1] = pkbf(e2, e3);
      }
    }
    bf16x8 pa[2];
    for (int m = 0; m < 2; m++) {
      asm("v_permlane32_swap_b32 %0, %1" : "+v"(cc[m][0]), "+v"(cc[m][2]));
      asm("v_permlane16_swap_b32 %0, %1" : "+v"(cc[m][0]), "+v"(cc[m][2]));
      asm("v_permlane32_swap_b32 %0, %1" : "+v"(cc[m][1]), "+v"(cc[m][3]));
      asm("v_permlane16_swap_b32 %0, %1" : "+v"(cc[m][1]), "+v"(cc[m][3]));
      union { unsigned u[4]; bf16x8 v; } pu;
      pu.u[0] = cc[m][0];
      pu.u[1] = cc[m][1];
      pu.u[2] = cc[m][2];
      pu.u[3] = cc[m][3];
      pa[m] = pu.v;
    }

    __builtin_amdgcn_s_setprio(1);
    for (int g = 0; g < 8; g++) {
      int swz = quad ^ (lcol & 3) ^ ((lcol >> 2) & 3);  // row = g*16+lcol
      bf16x8 vfr = *(const bf16x8*)(Vb + (size_t)(g * 16 + lcol) * 32 + swz * 8);
      for (int m = 0; m < 2; m++)
        o[m][g] = mfma16(pa[m], vfr, o[m][g]);
    }
    for (int m = 0; m < 2; m++)
      al[m] = mfma16(pa[m], ones, al[m]);
    __builtin_amdgcn_s_setprio(0);
  }

  for (int m = 0; m < 2; m++) {
    u16* op = ao + (size_t)(b * S_ + q0 + m * 16 + quad * 4) * D_ + h * DH_ + lcol;
    for (int r = 0; r < 4; r++) {
      float inv = 1.0f / al[m][r];
      for (int g = 0; g < 8; g++)
        op[(size_t)r * D_ + g * 16] = f2bf(o[m][g][r] * inv);
    }
  }
}

extern "C" void kernel_launch(void* const* d_in, const int* in_sizes, int n_in,
                              void* d_out, int out_size, void* d_ws, size_t ws_size,
                              hipStream_t stream)
{
  (void)in_sizes; (void)n_in; (void)out_size;
  const float* q  = (const float*)d_in[0];
  const float* k  = (const float*)d_in[1];
  const float* v  = (const float*)d_in[2];
  const float* Wq = (const float*)d_in[3];
  const float* bq = (const float*)d_in[4];
  const float* Wk = (const float*)d_in[5];
  const float* bk = (const float*)d_in[6];
  const float* Wv = (const float*)d_in[7];
  const float* bv = (const float*)d_in[8];
  const float* Wo = (const float*)d_in[9];
  const float* bo = (const float*)d_in[10];
  float* out = (float*)d_out;

  char* ws = (char*)d_ws;
  size_t off = 0;
  auto alloc = [&](size_t bytes) -> char* {
    char* p = ws + off; off += (bytes + 255) & ~(size_t)255; return p;
  };
  u16* xbf = (u16*)alloc((size_t)M_ * D_ * 2);    // k-cast, then q-cast, then ao
  u16* qh  = (u16*)alloc((size_t)M_ * D_ * 2);    // v-cast temp, then Q-proj out
  u16* kh  = (u16*)alloc((size_t)M_ * DH_ * 2);
  u16* vh  = (u16*)alloc((size_t)M_ * DH_ * 2);
  u16* vhT = (u16*)alloc((size_t)M_ * DH_ * 2);
  u16* WqT = (u16*)alloc((size_t)D_ * D_ * 2);
  u16* WkT = (u16*)alloc((size_t)DH_ * D_ * 2);
  u16* WvT = (u16*)alloc((size_t)DH_ * D_ * 2);
  u16* WoT = (u16*)alloc((size_t)D_ * D_ * 2);
  u16* ao  = xbf;   // xbf dead after Q-proj GEMM

  if (off > ws_size) return;  // diagnosable failure instead of OOB fault

  const int n4 = M_ * D_ / 4;

  transpose_bf<<<dim3(D_/32,  D_/32), dim3(32, 8), 0, stream>>>(Wq, WqT, D_, D_);
  transpose_bf<<<dim3(DH_/32, D_/32), dim3(32, 8), 0, stream>>>(Wk, WkT, D_, DH_);
  transpose_bf<<<dim3(DH_/32, D_/32), dim3(32, 8), 0, stream>>>(Wv, WvT, D_, DH_);
  transpose_bf<<<dim3(D_/32,  D_/32), dim3(32, 8), 0, stream>>>(Wo, WoT, D_, D_);

  // K + V cast (one dispatch): k->xbf, v->qh (qh free until Q-proj)
  cvt_bf16_2<<<dim3(n4 / 256, 2), dim3(256), 0, stream>>>(k, v, xbf, qh, n4);
  // K + V projection (one dispatch, 512 blocks)
  gemm_kv<<<dim3(M_/32, 1, 2), dim3(256), 0, stream>>>(
      xbf, qh, WkT, WvT, bk, bv, kh, vh);
  transpose_vh<<<dim3(DH_/32, S_/32, B_), dim3(32, 8), 0, stream>>>(vh, vhT);
  // Q projection (8-phase 256^2 GEMM, 256 blocks = 1/CU, XCD-swizzled)
  cvt_bf16<<<dim3(n4 / 256), dim3(256), 0, stream>>>(q, xbf, n4);
  gemm256<0><<<dim3(256), dim3(512), 0, stream>>>(xbf, WqT, bq, qh);

  // Attention (writes ao == xbf, merged heads)
  mqa_attn<<<dim3(S_/128, H_, B_), dim3(256), 0, stream>>>(qh, kh, vhT, ao);

  // Output projection (fp32 out + bias)
  gemm256<1><<<dim3(256), dim3(512), 0, stream>>>(ao, WoT, bo, out);
}

// Round 8
// 598.161 us; speedup vs baseline: 1.3568x; 1.0041x over previous
//
#include <hip/hip_runtime.h>
#include <stdint.h>

#define B_  4
#define S_  2048
#define D_  2048
#define H_  16
#define DH_ 128
#define M_  (B_*S_)

typedef unsigned short u16;
typedef __bf16 bf16x8 __attribute__((ext_vector_type(8)));
typedef float  f32x4  __attribute__((ext_vector_type(4)));
typedef float  f32x16 __attribute__((ext_vector_type(16)));
typedef u16    u16x4  __attribute__((ext_vector_type(4)));

__device__ __forceinline__ u16 f2bf(float f){
  unsigned x = __float_as_uint(f);
  x += 0x7fffu + ((x >> 16) & 1u);          // RNE
  return (u16)(x >> 16);
}

// v_cvt_pk_bf16_f32: D[15:0]=bf16(lo), D[31:16]=bf16(hi). No HIP builtin (m240).
__device__ __forceinline__ unsigned pkbf(float lo, float hi){
  unsigned r;
  asm("v_cvt_pk_bf16_f32 %0, %1, %2" : "=v"(r) : "v"(lo), "v"(hi));
  return r;
}

// Async global->LDS, 16B per lane. LDS dest = wave-uniform base + lane*16.
__device__ __forceinline__ void stage16(const void* g, void* lds_base){
  __builtin_amdgcn_global_load_lds(
      (const __attribute__((address_space(1))) void*)g,
      (__attribute__((address_space(3))) void*)lds_base, 16, 0, 0);
}

__device__ __forceinline__ f32x4 mfma16(bf16x8 a, bf16x8 b, f32x4 c){
  return __builtin_amdgcn_mfma_f32_16x16x32_bf16(a, b, c, 0, 0, 0);
}
__device__ __forceinline__ f32x16 mfma32(bf16x8 a, bf16x8 b, f32x16 c){
  return __builtin_amdgcn_mfma_f32_32x32x16_bf16(a, b, c, 0, 0, 0);
}

// ---------------- fp32 -> bf16 cast (vectorized) ----------------
__global__ void cvt_bf16(const float* __restrict__ s, u16* __restrict__ d, int n4){
  int i = blockIdx.x * 256 + threadIdx.x;
  if (i >= n4) return;
  float4 f = ((const float4*)s)[i];
  u16x4 u = { f2bf(f.x), f2bf(f.y), f2bf(f.z), f2bf(f.w) };
  ((u16x4*)d)[i] = u;
}

// Fused dual cast: blockIdx.y selects (s0->d0) or (s1->d1).
__global__ void cvt_bf16_2(const float* __restrict__ s0, const float* __restrict__ s1,
                           u16* __restrict__ d0, u16* __restrict__ d1, int n4){
  const float* s = blockIdx.y ? s1 : s0;
  u16*        d = blockIdx.y ? d1 : d0;
  int i = blockIdx.x * 256 + threadIdx.x;
  if (i >= n4) return;
  float4 f = ((const float4*)s)[i];
  u16x4 u = { f2bf(f.x), f2bf(f.y), f2bf(f.z), f2bf(f.w) };
  ((u16x4*)d)[i] = u;
}

// ---------------- W [K][N] fp32 -> WT [N][K] bf16 ----------------
__global__ void transpose_bf(const float* __restrict__ W, u16* __restrict__ WT, int K, int N){
  __shared__ float tl[32][33];
  int n0 = blockIdx.x * 32, k0 = blockIdx.y * 32;
  int tx = threadIdx.x, ty = threadIdx.y;     // block (32,8)
  for (int r = 0; r < 4; r++)
    tl[ty + 8*r][tx] = W[(size_t)(k0 + ty + 8*r) * N + n0 + tx];
  __syncthreads();
  for (int r = 0; r < 4; r++)
    WT[(size_t)(n0 + ty + 8*r) * K + k0 + tx] = f2bf(tl[tx][ty + 8*r]);
}

// -------- vh [B*S][DH] bf16 -> vhT [B][DH][S] bf16 --------
__global__ void transpose_vh(const u16* __restrict__ vh, u16* __restrict__ vhT){
  __shared__ u16 tl[32][33];
  int b = blockIdx.z, d0 = blockIdx.x * 32, s0 = blockIdx.y * 32;
  int tx = threadIdx.x, ty = threadIdx.y;     // block (32,8)
  for (int r = 0; r < 4; r++)
    tl[ty + 8*r][tx] = vh[(size_t)(b * S_ + s0 + ty + 8*r) * DH_ + d0 + tx];
  __syncthreads();
  for (int r = 0; r < 4; r++)
    vhT[(size_t)(b * DH_ + d0 + ty + 8*r) * S_ + s0 + tx] = tl[tx][ty + 8*r];
}

// ============ 256x256 GEMM v3: 2-phase K-loop, 32x32x16 frags ============
// r7 post-mortem: 4-thin-phase version was STALL-bound (~9-11k cyc/K-tile vs
// ~2k of pipe work; 8 barriers + lgkm drains with only 2 waves/SIMD). r8:
//  * 2 phases/K-tile (split by B-half): barriers 8 -> 4 per K-tile.
//  * 32x32x16 MFMA: instr count halved (32/K-tile/wave), +20% FLOP/issue-cyc.
//  * A-frags read once per K-tile (cached in regs across both phases):
//    ds_read_b128 48 -> 24 per K-tile per wave.
// Wave grid 4m x 2n: per wave, per (ah,bh) quadrant: 1 m-frag (ah*128+wr*32)
// x 2 n-frags (bh*128+wc*64+nf*32). acc[ah][bh][nf] f32x16 = 128 VGPR.
// Staging skeleton (verified r6/r7): per tile T: ph0 stages (T+1){B0,A1} into
// buf^1; ph1 stages (T+2)A0 at start (A0 reads done in ph0) and (T+2)B1 AFTER
// ph1's barrier+lgkm (B1 reads of all waves complete). vmcnt(4) at ph1 end
// (T+1 fully landed, T+2:{A0,B1} in flight); vmcnt(0) for T >= NT-2.
// LDS chunk swizzle: stored chunk = c ^ (row&7) via pre-swizzled global source.
template<int OUTF32>
__global__ __launch_bounds__(512, 1) void gemm256(const u16* __restrict__ A,
    const u16* __restrict__ BT, const float* __restrict__ bias, void* __restrict__ Cv)
{
  __shared__ alignas(16) u16 AB[2][2][2 * 128 * 64];   // [buf][A/B][half*8192 + row*64 + col]
  const int t = threadIdx.x, lane = t & 63, wave = t >> 6;
  const int hi = lane >> 5, l31 = lane & 31, l7 = lane & 7;
  const int wr = wave >> 1, wc = wave & 1;             // 4 m-groups x 2 n-groups
  const int bid = blockIdx.x;
  const int swz = (bid & 7) * 32 + (bid >> 3);         // XCD-contiguous (kept from r7)
  const int n0 = (swz & 7) * 256, m0 = (swz >> 3) * 256;
  const int NT = 2048 / 64;

  // Stage one half-tile (128 rows x 64 cols bf16 = 16KB): 2 gload_lds per thread.
  auto stageH = [&](const u16* g, int grow0, int kcol0, u16* lb){
    #pragma unroll
    for (int i = 0; i < 2; i++){
      int l = (i*8 + wave)*64 + lane;          // linear 16B-chunk id 0..1023
      int row = l >> 3, st = l & 7;
      int c = st ^ (row & 7);                  // pre-swizzled global chunk
      stage16(g + (size_t)(grow0 + row)*2048 + kcol0 + c*8, lb + (size_t)(i*8 + wave)*512);
    }
  };

  f32x16 acc[2][2][2] = {};                    // [ah][bh][nf] = 128 VGPR

  // Prologue: T0 all 4 halves + T1:{A0,B1}; vmcnt(4) -> T0 landed, 2 in flight.
  stageH(A,  m0,       0,  &AB[0][0][0]);
  stageH(BT, n0,       0,  &AB[0][1][0]);
  stageH(BT, n0 + 128, 0,  &AB[0][1][8192]);
  stageH(A,  m0 + 128, 0,  &AB[0][0][8192]);
  stageH(A,  m0,       64, &AB[1][0][0]);
  stageH(BT, n0 + 128, 64, &AB[1][1][8192]);
  asm volatile("s_waitcnt vmcnt(4)" ::: "memory");
  __builtin_amdgcn_s_barrier();

  for (int T = 0; T < NT; ++T) {
    const int bi = T & 1;
    const u16* Ab = &AB[bi][0][0];
    const u16* Bb = &AB[bi][1][0];
    bf16x8 af[2][4];                           // [ah][ks], cached across both phases
    bf16x8 bv[2][4];                           // [nf][ks], per phase

    // ---------------- phase 0 : bh = 0 ----------------
    #pragma unroll
    for (int ah = 0; ah < 2; ah++) {
      const u16* ap = Ab + (size_t)(ah*128 + wr*32 + l31) * 64;
      #pragma unroll
      for (int ks = 0; ks < 4; ks++)
        af[ah][ks] = *(const bf16x8*)(ap + (((ks*2 + hi) ^ l7) * 8));
    }
    #pragma unroll
    for (int nf = 0; nf < 2; nf++) {
      const u16* bp = Bb + (size_t)(wc*64 + nf*32 + l31) * 64;
      #pragma unroll
      for (int ks = 0; ks < 4; ks++)
        bv[nf][ks] = *(const bf16x8*)(bp + (((ks*2 + hi) ^ l7) * 8));
    }
    if (T + 1 < NT) {
      stageH(BT, n0,       (T+1)*64, &AB[(T+1)&1][1][0]);      // (T+1) B0
      stageH(A,  m0 + 128, (T+1)*64, &AB[(T+1)&1][0][8192]);   // (T+1) A1
    }
    __builtin_amdgcn_s_barrier();
    asm volatile("s_waitcnt lgkmcnt(0)" ::: "memory");
    __builtin_amdgcn_sched_barrier(0);
    __builtin_amdgcn_s_setprio(1);
    #pragma unroll
    for (int ah = 0; ah < 2; ah++)
      #pragma unroll
      for (int nf = 0; nf < 2; nf++)
        #pragma unroll
        for (int ks = 0; ks < 4; ks++)
          acc[ah][0][nf] = mfma32(af[ah][ks], bv[nf][ks], acc[ah][0][nf]);
    __builtin_amdgcn_s_setprio(0);
    __builtin_amdgcn_s_barrier();

    // ---------------- phase 1 : bh = 1 ----------------
    if (T + 2 < NT)
      stageH(A,  m0,       (T+2)*64, &AB[bi][0][0]);           // (T+2) A0 (A0 reads done ph0)
    #pragma unroll
    for (int nf = 0; nf < 2; nf++) {
      const u16* bp = Bb + (size_t)(128 + wc*64 + nf*32 + l31) * 64;
      #pragma unroll
      for (int ks = 0; ks < 4; ks++)
        bv[nf][ks] = *(const bf16x8*)(bp + (((ks*2 + hi) ^ l7) * 8));
    }
    __builtin_amdgcn_s_barrier();
    asm volatile("s_waitcnt lgkmcnt(0)" ::: "memory");
    __builtin_amdgcn_sched_barrier(0);
    if (T + 2 < NT)
      stageH(BT, n0 + 128, (T+2)*64, &AB[bi][1][8192]);        // (T+2) B1 (all B1 reads done)
    __builtin_amdgcn_s_setprio(1);
    #pragma unroll
    for (int ah = 0; ah < 2; ah++)
      #pragma unroll
      for (int nf = 0; nf < 2; nf++)
        #pragma unroll
        for (int ks = 0; ks < 4; ks++)
          acc[ah][1][nf] = mfma32(af[ah][ks], bv[nf][ks], acc[ah][1][nf]);
    __builtin_amdgcn_s_setprio(0);
    if (T < NT - 2) { asm volatile("s_waitcnt vmcnt(4)" ::: "memory"); }
    else            { asm volatile("s_waitcnt vmcnt(0)" ::: "memory"); }
    __builtin_amdgcn_s_barrier();
  }

  // Epilogue: C/D 32x32 mapping col=lane&31, row=(reg&3)+8*(reg>>2)+4*hi.
  #pragma unroll
  for (int ah = 0; ah < 2; ah++)
    #pragma unroll
    for (int bh = 0; bh < 2; bh++)
      #pragma unroll
      for (int nf = 0; nf < 2; nf++) {
        int col = n0 + bh*128 + wc*64 + nf*32 + l31;
        float bj = bias[col];
        int rowb = m0 + ah*128 + wr*32 + 4*hi;
        #pragma unroll
        for (int rg = 0; rg < 16; rg++) {
          int row = rowb + (rg & 3) + 8*(rg >> 2);
          float vv = acc[ah][bh][nf][rg] + bj;
          if (OUTF32) ((float*)Cv)[(size_t)row * 2048 + col] = vv;
          else        ((u16*)Cv)  [(size_t)row * 2048 + col] = f2bf(vv);
        }
      }
}

// -------- Fused K/V projection: C[M,128] = A[M,2048] @ BT[128,2048]^T + bias --------
__global__ __launch_bounds__(256) void gemm_kv(
    const u16* __restrict__ A0, const u16* __restrict__ A1,
    const u16* __restrict__ BT0, const u16* __restrict__ BT1,
    const float* __restrict__ b0, const float* __restrict__ b1,
    u16* __restrict__ C0, u16* __restrict__ C1)
{
  const int sel = blockIdx.z;
  const u16* A  = sel ? A1 : A0;
  const u16* BT = sel ? BT1 : BT0;
  const float* bias = sel ? b1 : b0;
  u16* C = sel ? C1 : C0;

  __shared__ alignas(16) u16 Al[32 * 32];    // 2 KB
  __shared__ alignas(16) u16 Bl[128 * 32];   // 8 KB
  const int t = threadIdx.x, lane = t & 63, wave = t >> 6;
  const int quad = lane >> 4, lcol = lane & 15;
  const int m0 = blockIdx.x * 32;

  f32x4 acc[2][2] = {};
  for (int k0 = 0; k0 < D_; k0 += 32) {
    if (t < 128) {
      int row = t >> 2, kc = t & 3;
      stage16(A + (size_t)(m0 + row) * D_ + k0 + kc * 8, Al + (wave * 64) * 8);
    } else {
      int bc = t - 128, row = bc >> 2, kc = bc & 3;
      stage16(BT + (size_t)row * D_ + k0 + kc * 8, Bl + ((wave - 2) * 64) * 8);
    }
    {
      int bc = t + 128, row = bc >> 2, kc = bc & 3;
      stage16(BT + (size_t)row * D_ + k0 + kc * 8, Bl + (128 + wave * 64) * 8);
    }
    if (t < 128) {
      int bc = t + 384, row = bc >> 2, kc = bc & 3;
      stage16(BT + (size_t)row * D_ + k0 + kc * 8, Bl + (384 + wave * 64) * 8);
    }
    __syncthreads();
    bf16x8 af[2], bfr[2];
    for (int i = 0; i < 2; i++)
      af[i]  = *(const bf16x8*)(Al + (i*16 + lcol) * 32 + quad * 8);
    for (int j = 0; j < 2; j++)
      bfr[j] = *(const bf16x8*)(Bl + (wave*32 + j*16 + lcol) * 32 + quad * 8);
    for (int i = 0; i < 2; i++)
      for (int j = 0; j < 2; j++)
        acc[i][j] = mfma16(af[i], bfr[j], acc[i][j]);
    __syncthreads();
  }
  for (int j = 0; j < 2; j++) {
    int n = wave * 32 + j * 16 + lcol;
    float bj = bias[n];
    for (int i = 0; i < 2; i++) {
      int mbase = m0 + i * 16 + quad * 4;
      for (int r = 0; r < 4; r++)
        C[(size_t)(mbase + r) * DH_ + n] = f2bf(acc[i][j][r] + bj);
    }
  }
}

// ---------------- Flash attention v6 (unchanged canary: ~205us) ----------------
__global__ __launch_bounds__(256, 3) void mqa_attn(const u16* __restrict__ qh,
    const u16* __restrict__ kh, const u16* __restrict__ vhT, u16* __restrict__ ao)
{
  __shared__ alignas(16) u16 Kl[2][32 * 128]; // [kv][dh], 16B-chunk swizzle st^(row&15)
  __shared__ alignas(16) u16 Vl[2][128 * 32]; // [dh][kv], swizzle st^(row&3)^((row>>2)&3)
  const int t = threadIdx.x, lane = t & 63, wave = t >> 6;
  const int quad = lane >> 4, lcol = lane & 15;
  const int b = blockIdx.z, h = blockIdx.y;
  const int q0 = blockIdx.x * 128 + wave * 32;         // 32 rows per wave
  const float sc2 = 0.12751743f;             // (1/sqrt(128)) * log2(e)

  bf16x8 qf[2][4];
  for (int m = 0; m < 2; m++) {
    const u16* qp = qh + (size_t)(b * S_ + q0 + m * 16 + lcol) * D_ + h * DH_ + quad * 8;
    for (int kk = 0; kk < 4; kk++) qf[m][kk] = *(const bf16x8*)(qp + kk * 32);
  }
  union { u16 u[8]; bf16x8 v; } one_u;
  for (int i = 0; i < 8; i++) one_u.u[i] = 0x3F80;
  const bf16x8 ones = one_u.v;

  f32x4 o[2][8] = {};
  f32x4 al[2] = {};
  const u16* kb = kh  + (size_t)b * S_ * DH_;
  const u16* vb = vhT + (size_t)b * DH_ * S_;

  auto stageKV = [&](int tt, int bi) {
    int kv0 = tt * 32;
    for (int p = 0; p < 2; p++) {
      int c = p * 256 + wave * 64 + lane;
      int row = c >> 4, st = c & 15;
      int kc = st ^ (row & 15);
      stage16(kb + (size_t)(kv0 + row) * DH_ + kc * 8, &Kl[bi][(p*256 + wave*64) * 8]);
    }
    for (int p = 0; p < 2; p++) {
      int c = p * 256 + wave * 64 + lane;
      int row = c >> 2, st = c & 3;
      int kc = st ^ (row & 3) ^ ((row >> 2) & 3);
      stage16(vb + (size_t)row * S_ + kv0 + kc * 8, &Vl[bi][(p*256 + wave*64) * 8]);
    }
  };

  stageKV(0, 0);
  for (int tt = 0; tt < S_ / 32; tt++) {
    const int bi = tt & 1;
    __syncthreads();                       // drains staging of tile tt; fences buf bi^1
    if (tt < S_ / 32 - 1) stageKV(tt + 1, bi ^ 1);   // in flight during compute

    const u16* Kb = &Kl[bi][0];
    const u16* Vb = &Vl[bi][0];

    unsigned cc[2][4];
    for (int kvf = 0; kvf < 2; kvf++) {
      f32x4 s[2] = {};
      const u16* kp = Kb + (size_t)(kvf * 16 + lcol) * 128;   // row&15 == lcol
      __builtin_amdgcn_s_setprio(1);
      for (int kk = 0; kk < 4; kk++) {
        int swz = (kk * 4 + quad) ^ lcol;
        bf16x8 kfr = *(const bf16x8*)(kp + swz * 8);
        for (int m = 0; m < 2; m++)
          s[m] = mfma16(kfr, qf[m][kk], s[m]);
      }
      __builtin_amdgcn_s_setprio(0);
      for (int m = 0; m < 2; m++) {
        float e0 = exp2f(s[m][0] * sc2), e1 = exp2f(s[m][1] * sc2);
        float e2 = exp2f(s[m][2] * sc2), e3 = exp2f(s[m][3] * sc2);
        cc[m][kvf * 2 + 0] = pkbf(e0, e1);
        cc[m][kvf * 2 + 1] = pkbf(e2, e3);
      }
    }
    bf16x8 pa[2];
    for (int m = 0; m < 2; m++) {
      asm("v_permlane32_swap_b32 %0, %1" : "+v"(cc[m][0]), "+v"(cc[m][2]));
      asm("v_permlane16_swap_b32 %0, %1" : "+v"(cc[m][0]), "+v"(cc[m][2]));
      asm("v_permlane32_swap_b32 %0, %1" : "+v"(cc[m][1]), "+v"(cc[m][3]));
      asm("v_permlane16_swap_b32 %0, %1" : "+v"(cc[m][1]), "+v"(cc[m][3]));
      union { unsigned u[4]; bf16x8 v; } pu;
      pu.u[0] = cc[m][0];
      pu.u[1] = cc[m][1];
      pu.u[2] = cc[m][2];
      pu.u[3] = cc[m][3];
      pa[m] = pu.v;
    }

    __builtin_amdgcn_s_setprio(1);
    for (int g = 0; g < 8; g++) {
      int swz = quad ^ (lcol & 3) ^ ((lcol >> 2) & 3);  // row = g*16+lcol
      bf16x8 vfr = *(const bf16x8*)(Vb + (size_t)(g * 16 + lcol) * 32 + swz * 8);
      for (int m = 0; m < 2; m++)
        o[m][g] = mfma16(pa[m], vfr, o[m][g]);
    }
    for (int m = 0; m < 2; m++)
      al[m] = mfma16(pa[m], ones, al[m]);
    __builtin_amdgcn_s_setprio(0);
  }

  for (int m = 0; m < 2; m++) {
    u16* op = ao + (size_t)(b * S_ + q0 + m * 16 + quad * 4) * D_ + h * DH_ + lcol;
    for (int r = 0; r < 4; r++) {
      float inv = 1.0f / al[m][r];
      for (int g = 0; g < 8; g++)
        op[(size_t)r * D_ + g * 16] = f2bf(o[m][g][r] * inv);
    }
  }
}

extern "C" void kernel_launch(void* const* d_in, const int* in_sizes, int n_in,
                              void* d_out, int out_size, void* d_ws, size_t ws_size,
                              hipStream_t stream)
{
  (void)in_sizes; (void)n_in; (void)out_size;
  const float* q  = (const float*)d_in[0];
  const float* k  = (const float*)d_in[1];
  const float* v  = (const float*)d_in[2];
  const float* Wq = (const float*)d_in[3];
  const float* bq = (const float*)d_in[4];
  const float* Wk = (const float*)d_in[5];
  const float* bk = (const float*)d_in[6];
  const float* Wv = (const float*)d_in[7];
  const float* bv = (const float*)d_in[8];
  const float* Wo = (const float*)d_in[9];
  const float* bo = (const float*)d_in[10];
  float* out = (float*)d_out;

  char* ws = (char*)d_ws;
  size_t off = 0;
  auto alloc = [&](size_t bytes) -> char* {
    char* p = ws + off; off += (bytes + 255) & ~(size_t)255; return p;
  };
  u16* xbf = (u16*)alloc((size_t)M_ * D_ * 2);    // k-cast, then q-cast, then ao
  u16* qh  = (u16*)alloc((size_t)M_ * D_ * 2);    // v-cast temp, then Q-proj out
  u16* kh  = (u16*)alloc((size_t)M_ * DH_ * 2);
  u16* vh  = (u16*)alloc((size_t)M_ * DH_ * 2);
  u16* vhT = (u16*)alloc((size_t)M_ * DH_ * 2);
  u16* WqT = (u16*)alloc((size_t)D_ * D_ * 2);
  u16* WkT = (u16*)alloc((size_t)DH_ * D_ * 2);
  u16* WvT = (u16*)alloc((size_t)DH_ * D_ * 2);
  u16* WoT = (u16*)alloc((size_t)D_ * D_ * 2);
  u16* ao  = xbf;   // xbf dead after Q-proj GEMM

  if (off > ws_size) return;  // diagnosable failure instead of OOB fault

  const int n4 = M_ * D_ / 4;

  transpose_bf<<<dim3(D_/32,  D_/32), dim3(32, 8), 0, stream>>>(Wq, WqT, D_, D_);
  transpose_bf<<<dim3(DH_/32, D_/32), dim3(32, 8), 0, stream>>>(Wk, WkT, D_, DH_);
  transpose_bf<<<dim3(DH_/32, D_/32), dim3(32, 8), 0, stream>>>(Wv, WvT, D_, DH_);
  transpose_bf<<<dim3(D_/32,  D_/32), dim3(32, 8), 0, stream>>>(Wo, WoT, D_, D_);

  // K + V cast (one dispatch): k->xbf, v->qh (qh free until Q-proj)
  cvt_bf16_2<<<dim3(n4 / 256, 2), dim3(256), 0, stream>>>(k, v, xbf, qh, n4);
  // K + V projection (one dispatch, 512 blocks)
  gemm_kv<<<dim3(M_/32, 1, 2), dim3(256), 0, stream>>>(
      xbf, qh, WkT, WvT, bk, bv, kh, vh);
  transpose_vh<<<dim3(DH_/32, S_/32, B_), dim3(32, 8), 0, stream>>>(vh, vhT);
  // Q projection (2-phase 256^2 GEMM, 256 blocks = 1/CU, XCD-swizzled)
  cvt_bf16<<<dim3(n4 / 256), dim3(256), 0, stream>>>(q, xbf, n4);
  gemm256<0><<<dim3(256), dim3(512), 0, stream>>>(xbf, WqT, bq, qh);

  // Attention (writes ao == xbf, merged heads)
  mqa_attn<<<dim3(S_/128, H_, B_), dim3(256), 0, stream>>>(qh, kh, vhT, ao);

  // Output projection (fp32 out + bias)
  gemm256<1><<<dim3(256), dim3(512), 0, stream>>>(ao, WoT, bo, out);
}